// Round 8
// baseline (489.292 us; speedup 1.0000x reference)
//
#include <hip/hip_runtime.h>
#include <hip/hip_bf16.h>

// Problem constants (match reference)
#define NN 100000   // nodes
#define NE 640000   // edges
#define NG 64       // graphs
#define BN_EPS 1e-5f

#define BS 256      // block size
#define SCAN_BS 1024
#define NB_SCAN ((NN + SCAN_BS - 1) / SCAN_BS)   // 98
#define PNPB 256    // nodes per block in pool

typedef __attribute__((ext_vector_type(8))) unsigned short ushort8_t;
typedef __attribute__((ext_vector_type(4))) unsigned short ushort4_t;
typedef __attribute__((ext_vector_type(8))) short bf16x8_t;    // MFMA A/B frag (4 VGPR)
typedef __attribute__((ext_vector_type(4))) float floatx4_t;   // MFMA C/D frag

static inline int cdiv(long long a, int b) { return (int)((a + b - 1) / b); }

__device__ __forceinline__ float bf2f(unsigned short u) {
    union { unsigned int i; float f; } c; c.i = ((unsigned int)u) << 16; return c.f;
}
__device__ __forceinline__ unsigned short f2bf(float f) {   // RNE
    unsigned int u = __float_as_uint(f);
    u += 0x7fffu + ((u >> 16) & 1u);
    return (unsigned short)(u >> 16);
}

// ---------------- degree: deg[s] += 1 for non-self-loop edges ----------------
__global__ void deg_kernel(const int* __restrict__ src, const int* __restrict__ dst,
                           float* __restrict__ deg, int E) {
    int e = blockIdx.x * blockDim.x + threadIdx.x;
    if (e >= E) return;
    int s = src[e], d = dst[e];
    if (s != d) unsafeAtomicAdd(&deg[s], 1.0f);
}

// ---- edge weights + CSR histogram: w[e] = -dinv[src]*dinv[dst]; cnt_n[dst]++ if w!=0 ----
__global__ void wgt_hist_kernel(const int* __restrict__ src, const int* __restrict__ dst,
                                const float* __restrict__ deg, float* __restrict__ w,
                                int* __restrict__ cnt_n, int E) {
    int e = blockIdx.x * blockDim.x + threadIdx.x;
    if (e >= E) return;
    int s = src[e], d = dst[e];
    float wv = 0.0f;
    if (s != d) {
        float ds_ = deg[s], dd = deg[d];
        float a = ds_ > 0.0f ? rsqrtf(ds_) : 0.0f;
        float b = dd  > 0.0f ? rsqrtf(dd)  : 0.0f;
        wv = -a * b;
    }
    w[e] = wv;
    if (wv != 0.0f) atomicAdd(&cnt_n[d], 1);
}

// ---------------- 3-kernel exclusive scan of cnt_n -> row_start ----------------
__global__ void scan1_kernel(const int* __restrict__ cnt, int* __restrict__ excl,
                             int* __restrict__ bsum, int N) {
    __shared__ int s[SCAN_BS];
    int t = threadIdx.x;
    int i = blockIdx.x * SCAN_BS + t;
    int v = (i < N) ? cnt[i] : 0;
    s[t] = v;
    __syncthreads();
    for (int off = 1; off < SCAN_BS; off <<= 1) {
        int add = (t >= off) ? s[t - off] : 0;
        __syncthreads();
        s[t] += add;
        __syncthreads();
    }
    if (i < N) excl[i] = s[t] - v;   // exclusive
    if (t == SCAN_BS - 1) bsum[blockIdx.x] = s[t];
}

__global__ void scan2_kernel(int* __restrict__ bsum, int* __restrict__ total, int NB) {
    __shared__ int s[128];
    int t = threadIdx.x;
    int v = (t < NB) ? bsum[t] : 0;
    s[t] = v;
    __syncthreads();
    for (int off = 1; off < 128; off <<= 1) {
        int add = (t >= off) ? s[t - off] : 0;
        __syncthreads();
        s[t] += add;
        __syncthreads();
    }
    if (t < NB) bsum[t] = s[t] - v;  // exclusive
    if (t == 127) *total = s[127];
}

__global__ void scan3_kernel(int* __restrict__ excl, const int* __restrict__ bsum, int N) {
    int i = blockIdx.x * blockDim.x + threadIdx.x;
    if (i < N) excl[i] += bsum[i >> 10];   // SCAN_BS = 1024
}

// ---- scatter edges into CSR slots; col+val interleaved (one 8B store = one dirty line) ----
__global__ void scatter_kernel(const int* __restrict__ src, const int* __restrict__ dst,
                               const float* __restrict__ w, const int* __restrict__ row_start,
                               int* __restrict__ fill, int2* __restrict__ cv, int E) {
    int e = blockIdx.x * blockDim.x + threadIdx.x;
    if (e >= E) return;
    float wv = w[e];
    if (wv == 0.0f) return;
    int d = dst[e];
    int pos = row_start[d] + atomicAdd(&fill[d], 1);
    cv[pos] = make_int2(src[e], __float_as_int(wv));
}

// ---- degree-bin histogram (LDS-aggregated; bin = min(deg,63)) ----
__global__ void dhist_kernel(const int* __restrict__ cnt_n, int* __restrict__ dhist, int N) {
    __shared__ int lh[64];
    int t = threadIdx.x;
    if (t < 64) lh[t] = 0;
    __syncthreads();
    int i = blockIdx.x * blockDim.x + t;
    if (i < N) atomicAdd(&lh[min(cnt_n[i], 63)], 1);
    __syncthreads();
    if (t < 64 && lh[t] > 0) atomicAdd(&dhist[t], lh[t]);
}

// ---- exclusive scan of the 64 degree bins, in place (single wave) ----
__global__ void dscan_kernel(int* __restrict__ dhist) {
    int t = threadIdx.x;           // 64 threads
    int orig = dhist[t];
    int v = orig;
    for (int o = 1; o < 64; o <<= 1) {
        int n = __shfl_up(v, o, 64);
        if (t >= o) v += n;
    }
    dhist[t] = v - orig;           // exclusive
}

// ---- place rows into degree-sorted order (two-level: LDS offsets + 1 global atomic/bin) ----
__global__ void rorder_kernel(const int* __restrict__ cnt_n, const int* __restrict__ dstart,
                              int* __restrict__ dfill, int* __restrict__ ro, int N) {
    __shared__ int lh[64];
    __shared__ int lbase[64];
    int t = threadIdx.x;
    if (t < 64) lh[t] = 0;
    __syncthreads();
    int i = blockIdx.x * blockDim.x + t;
    int d = 0, loc = 0;
    bool act = (i < N);
    if (act) {
        d = min(cnt_n[i], 63);
        loc = atomicAdd(&lh[d], 1);
    }
    __syncthreads();
    if (t < 64 && lh[t] > 0) lbase[t] = atomicAdd(&dfill[t], lh[t]);
    __syncthreads();
    if (act) ro[dstart[d] + lbase[d] + loc] = i;
}

// ---- prepB: arrange Bcat = [W2 | W1 | W0-W2] (FI x 3FO) into MFMA B-fragment layout ----
template <int FI, int FO>
__global__ void prepB_kernel(const float* __restrict__ W, unsigned short* __restrict__ Bfrag) {
    constexpr int NT = 3 * FO / 16;
    constexpr int NS = FI / 32;
    int id = blockIdx.x * blockDim.x + threadIdx.x;
    if (id >= NT * NS * 64) return;
    int lane = id & 63;
    int s = (id >> 6) % NS;
    int t = (id >> 6) / NS;
    int n = t * 16 + (lane & 15);
    int kbase = s * 32 + (lane >> 4) * 8;
    int sec = n / FO;        // 0 -> W2, 1 -> W1, 2 -> W0 - W2
    int nc  = n % FO;
    ushort8_t out;
#pragma unroll
    for (int j = 0; j < 8; j++) {
        int k = kbase + j;
        float v;
        if (sec == 0)      v = W[(size_t)(2 * FI + k) * FO + nc];
        else if (sec == 1) v = W[(size_t)(1 * FI + k) * FO + nc];
        else               v = W[(size_t)(0 * FI + k) * FO + nc]
                             - W[(size_t)(2 * FI + k) * FO + nc];
        out[j] = f2bf(v);
    }
    *(ushort8_t*)(Bfrag + (size_t)id * 8) = out;
}

// ---- MFMA gemm3: Ubf = bf16(x@W2), T = x@W1, S = x@(W0-W2); no LDS, no barriers ----
template <int FI, int FO>
__global__ __launch_bounds__(256) void gemmM_kernel(
        const float* __restrict__ x, const unsigned short* __restrict__ Bfrag,
        float* __restrict__ T, float* __restrict__ S,
        unsigned short* __restrict__ Ubf, int N) {
    constexpr int NT = 3 * FO / 16;   // n-tiles
    constexpr int NS = FI / 32;       // k-steps
    const int lane = threadIdx.x & 63;
    const int wave = threadIdx.x >> 6;
    const int m0   = blockIdx.x * 64 + wave * 16;
    if (m0 >= N) return;
    const int quad = lane >> 4;
    const int mrow = m0 + (lane & 15);

    floatx4_t acc[NT];
#pragma unroll
    for (int t = 0; t < NT; t++) acc[t] = (floatx4_t){0.f, 0.f, 0.f, 0.f};

#pragma unroll
    for (int s = 0; s < NS; s++) {
        bf16x8_t a;
        if (mrow < N) {
            const float* ap = x + (size_t)mrow * FI + s * 32 + quad * 8;
            float4 a0 = *(const float4*)(ap);
            float4 a1 = *(const float4*)(ap + 4);
            a[0] = (short)f2bf(a0.x); a[1] = (short)f2bf(a0.y);
            a[2] = (short)f2bf(a0.z); a[3] = (short)f2bf(a0.w);
            a[4] = (short)f2bf(a1.x); a[5] = (short)f2bf(a1.y);
            a[6] = (short)f2bf(a1.z); a[7] = (short)f2bf(a1.w);
        } else {
            a = (bf16x8_t){0, 0, 0, 0, 0, 0, 0, 0};
        }
#pragma unroll
        for (int t = 0; t < NT; t++) {
            bf16x8_t b = *(const bf16x8_t*)(Bfrag + ((size_t)(t * NS + s) * 64 + lane) * 8);
            acc[t] = __builtin_amdgcn_mfma_f32_16x16x32_bf16(a, b, acc[t], 0, 0, 0);
        }
    }
    // C/D layout: col = lane&15, row = quad*4 + reg   [verified m89/m91]
#pragma unroll
    for (int t = 0; t < NT; t++) {
        int n   = t * 16 + (lane & 15);
        int sec = (t * 16) / FO;          // compile-time per t (FO multiple of 16)
        int nc  = n % FO;
#pragma unroll
        for (int r = 0; r < 4; r++) {
            int m = m0 + quad * 4 + r;
            if (m >= N) continue;
            float v = acc[t][r];
            size_t o = (size_t)m * FO + nc;
            if (sec == 0)      Ubf[o] = f2bf(v);
            else if (sec == 1) T[o] = v;
            else               S[o] = v;
        }
    }
}

// ---- propA8: Obf[i] = bf16( T[i] + 2 * sum_p val[p]*Ubf[col[p]] ) ----
// Thread per (row, 8-feature chunk); rows visited in degree-sorted order via ro[]
// so all rows in a wave share the same degree (no divergence).
template <int FO>
__global__ void propA8_kernel(const unsigned short* __restrict__ Ubf,
                              const float* __restrict__ T,
                              const int* __restrict__ rs, const int2* __restrict__ cv,
                              const int* __restrict__ ro,
                              unsigned short* __restrict__ Obf, int N) {
    constexpr int PER = FO / 8;
    unsigned idx = blockIdx.x * blockDim.x + threadIdx.x;
    if (idx >= (unsigned)N * PER) return;
    int i = ro[idx / PER];
    int c = (idx & (PER - 1)) * 8;
    int beg = rs[i], end = rs[i + 1];
    float acc[8] = {0.f, 0.f, 0.f, 0.f, 0.f, 0.f, 0.f, 0.f};
    for (int p = beg; p < end; ++p) {
        int2 e = cv[p];
        float wv = __int_as_float(e.y);
        ushort8_t u = *(const ushort8_t*)(Ubf + (size_t)e.x * FO + c);
#pragma unroll
        for (int j = 0; j < 8; j++) acc[j] = fmaf(wv, bf2f(u[j]), acc[j]);
    }
    const float* tr = T + (size_t)i * FO + c;
    float4 t0 = *(const float4*)(tr);
    float4 t1 = *(const float4*)(tr + 4);
    const float ts[8] = {t0.x, t0.y, t0.z, t0.w, t1.x, t1.y, t1.z, t1.w};
    ushort8_t o;
#pragma unroll
    for (int j = 0; j < 8; j++) o[j] = f2bf(ts[j] + 2.f * acc[j]);
    *(ushort8_t*)(Obf + (size_t)i * FO + c) = o;
}

// ---- propC8: h[i] = leaky_relu(BN(S[i] + sum_p val[p]*Bbf[col[p]] + b))  (h may == S) ----
template <int FO>
__global__ void propC8_kernel(const unsigned short* __restrict__ Bbf,
                              const float* __restrict__ S,
                              const int* __restrict__ rs, const int2* __restrict__ cv,
                              const int* __restrict__ ro,
                              const float* __restrict__ b, const float* __restrict__ g,
                              const float* __restrict__ be, const float* __restrict__ m,
                              const float* __restrict__ vv, float* __restrict__ h, int N) {
    constexpr int PER = FO / 8;
    unsigned idx = blockIdx.x * blockDim.x + threadIdx.x;
    if (idx >= (unsigned)N * PER) return;
    int i = ro[idx / PER];
    int c = (idx & (PER - 1)) * 8;
    int beg = rs[i], end = rs[i + 1];
    float acc[8] = {0.f, 0.f, 0.f, 0.f, 0.f, 0.f, 0.f, 0.f};
    for (int p = beg; p < end; ++p) {
        int2 e = cv[p];
        float wv = __int_as_float(e.y);
        ushort8_t u = *(const ushort8_t*)(Bbf + (size_t)e.x * FO + c);
#pragma unroll
        for (int j = 0; j < 8; j++) acc[j] = fmaf(wv, bf2f(u[j]), acc[j]);
    }
    const float* sr = S + (size_t)i * FO + c;
    float4 s0 = *(const float4*)(sr);
    float4 s1 = *(const float4*)(sr + 4);
    const float ss[8] = {s0.x, s0.y, s0.z, s0.w, s1.x, s1.y, s1.z, s1.w};
    float out[8];
#pragma unroll
    for (int j = 0; j < 8; j++) {
        int f = c + j;
        float A = g[f] * rsqrtf(vv[f] + BN_EPS);
        float B = be[f] - (m[f] - b[f]) * A;
        float y = (ss[j] + acc[j]) * A + B;
        out[j] = y > 0.0f ? y : 0.01f * y;
    }
    float* hr = h + (size_t)i * FO + c;
    *(float4*)(hr)     = make_float4(out[0], out[1], out[2], out[3]);
    *(float4*)(hr + 4) = make_float4(out[4], out[5], out[6], out[7]);
}

// ---- mean pool v3: thread = (node-lane, feature-quad); float4 loads; register
// accum flushed on graph change to LDS table; few global atomics per block ----
__global__ __launch_bounds__(256) void pool3_kernel(
        const float* __restrict__ h, const int* __restrict__ batch,
        float* __restrict__ pool, float* __restrict__ cnt, int N) {
    __shared__ float sp[NG * 16];
    __shared__ float sc[NG];
    int t = threadIdx.x;
    for (int i = t; i < NG * 16; i += 256) sp[i] = 0.f;
    for (int i = t; i < NG; i += 256) sc[i] = 0.f;
    __syncthreads();
    const int f4 = (t & 3) * 4;      // feature quad
    const int nl = t >> 2;           // node lane 0..63
    const int base = blockIdx.x * PNPB;
    const int nEnd = min(base + PNPB, N);
    float4 acc = make_float4(0.f, 0.f, 0.f, 0.f);
    float cacc = 0.f;
    int gcur = -1;
    for (int n = base + nl; n < nEnd; n += 64) {
        int g = batch[n];
        if (g != gcur) {
            if (gcur >= 0) {
                atomicAdd(&sp[gcur * 16 + f4 + 0], acc.x);
                atomicAdd(&sp[gcur * 16 + f4 + 1], acc.y);
                atomicAdd(&sp[gcur * 16 + f4 + 2], acc.z);
                atomicAdd(&sp[gcur * 16 + f4 + 3], acc.w);
                if (f4 == 0) atomicAdd(&sc[gcur], cacc);
            }
            gcur = g; acc = make_float4(0.f, 0.f, 0.f, 0.f); cacc = 0.f;
        }
        float4 hv = *(const float4*)(h + (size_t)n * 16 + f4);
        acc.x += hv.x; acc.y += hv.y; acc.z += hv.z; acc.w += hv.w;
        cacc += 1.f;
    }
    if (gcur >= 0) {
        atomicAdd(&sp[gcur * 16 + f4 + 0], acc.x);
        atomicAdd(&sp[gcur * 16 + f4 + 1], acc.y);
        atomicAdd(&sp[gcur * 16 + f4 + 2], acc.z);
        atomicAdd(&sp[gcur * 16 + f4 + 3], acc.w);
        if (f4 == 0) atomicAdd(&sc[gcur], cacc);
    }
    __syncthreads();
    for (int i = t; i < NG * 16; i += 256)
        if (sp[i] != 0.f) unsafeAtomicAdd(&pool[i], sp[i]);
    for (int i = t; i < NG; i += 256)
        if (sc[i] != 0.f) unsafeAtomicAdd(&cnt[i], sc[i]);
}

// ---------------- final linear head ----------------
__global__ void final_kernel(const float* __restrict__ pool, const float* __restrict__ cnt,
                             const float* __restrict__ lw, const float* __restrict__ lb,
                             float* __restrict__ out) {
    int idx = threadIdx.x;
    if (idx >= NG * 2) return;
    int g = idx >> 1;
    int c = idx & 1;
    float inv = 1.0f / fmaxf(cnt[g], 1.0f);
    float acc = 0.0f;
#pragma unroll
    for (int f = 0; f < 16; f++) acc += pool[g * 16 + f] * lw[c * 16 + f];
    out[idx] = acc * inv + lb[c];
}

extern "C" void kernel_launch(void* const* d_in, const int* in_sizes, int n_in,
                              void* d_out, int out_size, void* d_ws, size_t ws_size,
                              hipStream_t stream) {
    const float* x    = (const float*)d_in[0];
    const int*   ei   = (const int*)d_in[1];
    const int*   batch= (const int*)d_in[2];
    const float* W1 = (const float*)d_in[3];
    const float* b1 = (const float*)d_in[4];
    const float* g1 = (const float*)d_in[5];
    const float* be1= (const float*)d_in[6];
    const float* m1 = (const float*)d_in[7];
    const float* v1 = (const float*)d_in[8];
    const float* W2 = (const float*)d_in[9];
    const float* b2 = (const float*)d_in[10];
    const float* g2 = (const float*)d_in[11];
    const float* be2= (const float*)d_in[12];
    const float* m2 = (const float*)d_in[13];
    const float* v2 = (const float*)d_in[14];
    const float* W3 = (const float*)d_in[15];
    const float* b3 = (const float*)d_in[16];
    const float* g3 = (const float*)d_in[17];
    const float* be3= (const float*)d_in[18];
    const float* m3 = (const float*)d_in[19];
    const float* v3 = (const float*)d_in[20];
    const float* lw = (const float*)d_in[21];
    const float* lb = (const float*)d_in[22];

    const int* src = ei;            // edge_index[0]
    const int* dst = ei + NE;       // edge_index[1]

    float* ws = (float*)d_ws;
    // ---- workspace layout (4-byte units, 16B-aligned) ----
    size_t off = 0;
    float* deg   = ws + off; off += NN;
    int*   cnt_n = (int*)(ws + off); off += NN;
    int*   fill  = (int*)(ws + off); off += NN;
    float* pool  = ws + off; off += NG * 16;
    float* cnt   = ws + off; off += NG;
    int*   dhist = (int*)(ws + off); off += 64;
    int*   dfill = (int*)(ws + off); off += 64;
    size_t zero_bytes = off * sizeof(float);       // one memset covers all of the above
    float* w     = ws + off; off += NE;              // overlaid by ro after edge-scatter
    int*   rs    = (int*)(ws + off); off += NN + 4;  // row_start [N+1], padded
    int2*  cv    = (int2*)(ws + off); off += 2 * (size_t)NE;  // interleaved {col,val}
    int*   bsum  = (int*)(ws + off); off += 128;
    float* A    = ws + off; off += (size_t)NN * 64;          // T buffers
    float* Bb   = ws + off; off += (size_t)NN * 64;          // S1 / h1
    float* D    = ws + off; off += (size_t)NN * 32;          // S2 / h2
    float* C16  = ws + off; off += (size_t)NN * 16;          // S3 / h3
    unsigned short* Ubf  = (unsigned short*)(ws + off); off += (size_t)NN * 32;  // NN*64 bf16
    unsigned short* Bbbf = (unsigned short*)(ws + off); off += (size_t)NN * 32;  // NN*64 bf16

    // B-fragment buffers overlay `deg` (dead after wgt_hist): ~65 KB << 400 KB
    unsigned short* Bf1 = (unsigned short*)deg;              // 12*4*64*8 = 24576 bf16
    unsigned short* Bf2 = Bf1 + 12 * 4 * 64 * 8;             //  6*2*64*8 =  6144 bf16
    unsigned short* Bf3 = Bf2 + 6 * 2 * 64 * 8;              //  3*1*64*8 =  1536 bf16
    // ro (degree-sorted row order) overlays `w` (dead after edge-scatter)
    int* ro = (int*)w;

    hipMemsetAsync(ws, 0, zero_bytes, stream);

    // ---- edge weights + CSR build ----
    deg_kernel<<<cdiv(NE, BS), BS, 0, stream>>>(src, dst, deg, NE);
    wgt_hist_kernel<<<cdiv(NE, BS), BS, 0, stream>>>(src, dst, deg, w, cnt_n, NE);
    // deg now dead -> overlay Bfrag buffers
    prepB_kernel<128, 64><<<cdiv(12 * 4 * 64, BS), BS, 0, stream>>>(W1, Bf1);
    prepB_kernel<64, 32><<<cdiv(6 * 2 * 64, BS), BS, 0, stream>>>(W2, Bf2);
    prepB_kernel<32, 16><<<cdiv(3 * 1 * 64, BS), BS, 0, stream>>>(W3, Bf3);
    scan1_kernel<<<NB_SCAN, SCAN_BS, 0, stream>>>(cnt_n, rs, bsum, NN);
    scan2_kernel<<<1, 128, 0, stream>>>(bsum, rs + NN, NB_SCAN);
    scan3_kernel<<<cdiv(NN, BS), BS, 0, stream>>>(rs, bsum, NN);
    scatter_kernel<<<cdiv(NE, BS), BS, 0, stream>>>(src, dst, w, rs, fill, cv, NE);
    // ---- degree-sorted row order (w dead -> ro overlay) ----
    dhist_kernel<<<cdiv(NN, BS), BS, 0, stream>>>(cnt_n, dhist, NN);
    dscan_kernel<<<1, 64, 0, stream>>>(dhist);
    rorder_kernel<<<cdiv(NN, BS), BS, 0, stream>>>(cnt_n, dhist, dfill, ro, NN);

    // ---- layer 1: 128 -> 64 ----
    gemmM_kernel<128, 64><<<cdiv(NN, 64), 256, 0, stream>>>(x, Bf1, A, Bb, Ubf, NN);
    propA8_kernel<64><<<cdiv((long long)NN * 8, BS), BS, 0, stream>>>(Ubf, A, rs, cv, ro, Bbbf, NN);
    propC8_kernel<64><<<cdiv((long long)NN * 8, BS), BS, 0, stream>>>(Bbbf, Bb, rs, cv, ro,
                                                                      b1, g1, be1, m1, v1, Bb, NN);
    // ---- layer 2: 64 -> 32 ----
    gemmM_kernel<64, 32><<<cdiv(NN, 64), 256, 0, stream>>>(Bb, Bf2, A, D, Ubf, NN);
    propA8_kernel<32><<<cdiv((long long)NN * 4, BS), BS, 0, stream>>>(Ubf, A, rs, cv, ro, Bbbf, NN);
    propC8_kernel<32><<<cdiv((long long)NN * 4, BS), BS, 0, stream>>>(Bbbf, D, rs, cv, ro,
                                                                      b2, g2, be2, m2, v2, D, NN);
    // ---- layer 3: 32 -> 16 ----
    gemmM_kernel<32, 16><<<cdiv(NN, 64), 256, 0, stream>>>(D, Bf3, A, C16, Ubf, NN);
    propA8_kernel<16><<<cdiv((long long)NN * 2, BS), BS, 0, stream>>>(Ubf, A, rs, cv, ro, Bbbf, NN);
    propC8_kernel<16><<<cdiv((long long)NN * 2, BS), BS, 0, stream>>>(Bbbf, C16, rs, cv, ro,
                                                                      b3, g3, be3, m3, v3, C16, NN);
    // ---- pool + head ----
    pool3_kernel<<<cdiv(NN, PNPB), 256, 0, stream>>>(C16, batch, pool, cnt, NN);
    final_kernel<<<1, 128, 0, stream>>>(pool, cnt, lw, lb, (float*)d_out);
}

// Round 9
// 447.040 us; speedup vs baseline: 1.0945x; 1.0945x over previous
//
#include <hip/hip_runtime.h>
#include <hip/hip_bf16.h>

// Problem constants (match reference)
#define NN 100000   // nodes
#define NE 640000   // edges
#define NG 64       // graphs
#define BN_EPS 1e-5f

#define BS 256      // block size
#define SCAN_BS 1024
#define NB_SCAN ((NN + SCAN_BS - 1) / SCAN_BS)   // 98
#define PNPB 256    // nodes per block in pool
#define MAXSLOT (NE + 7 * NN)   // padded CSR capacity (pad-to-8 per row)

typedef __attribute__((ext_vector_type(8))) unsigned short ushort8_t;
typedef __attribute__((ext_vector_type(4))) unsigned short ushort4_t;
typedef __attribute__((ext_vector_type(8))) short bf16x8_t;    // MFMA A/B frag (4 VGPR)
typedef __attribute__((ext_vector_type(4))) float floatx4_t;   // MFMA C/D frag

static inline int cdiv(long long a, int b) { return (int)((a + b - 1) / b); }

__device__ __forceinline__ float bf2f(unsigned short u) {
    union { unsigned int i; float f; } c; c.i = ((unsigned int)u) << 16; return c.f;
}
__device__ __forceinline__ unsigned short f2bf(float f) {   // RNE
    unsigned int u = __float_as_uint(f);
    u += 0x7fffu + ((u >> 16) & 1u);
    return (unsigned short)(u >> 16);
}

// ---------------- degree: deg[s] += 1 for non-self-loop edges ----------------
__global__ void deg_kernel(const int* __restrict__ src, const int* __restrict__ dst,
                           float* __restrict__ deg, int E) {
    int e = blockIdx.x * blockDim.x + threadIdx.x;
    if (e >= E) return;
    int s = src[e], d = dst[e];
    if (s != d) unsafeAtomicAdd(&deg[s], 1.0f);
}

// ---- edge weights + CSR histogram: w[e] = -dinv[src]*dinv[dst]; cnt_n[dst]++ if w!=0 ----
__global__ void wgt_hist_kernel(const int* __restrict__ src, const int* __restrict__ dst,
                                const float* __restrict__ deg, float* __restrict__ w,
                                int* __restrict__ cnt_n, int E) {
    int e = blockIdx.x * blockDim.x + threadIdx.x;
    if (e >= E) return;
    int s = src[e], d = dst[e];
    float wv = 0.0f;
    if (s != d) {
        float ds_ = deg[s], dd = deg[d];
        float a = ds_ > 0.0f ? rsqrtf(ds_) : 0.0f;
        float b = dd  > 0.0f ? rsqrtf(dd)  : 0.0f;
        wv = -a * b;
    }
    w[e] = wv;
    if (wv != 0.0f) atomicAdd(&cnt_n[d], 1);
}

// ---- 3-kernel exclusive scan of PADDED counts (ceil8) -> row_start ----
// Padding to 8 slots (64B) isolates each row's cv range to its own cache lines,
// killing the cross-XCD false sharing that amplified scatter writes 8x (R8 PMC).
__global__ void scan1_kernel(const int* __restrict__ cnt, int* __restrict__ excl,
                             int* __restrict__ bsum, int N) {
    __shared__ int s[SCAN_BS];
    int t = threadIdx.x;
    int i = blockIdx.x * SCAN_BS + t;
    int v = (i < N) ? ((cnt[i] + 7) & ~7) : 0;
    s[t] = v;
    __syncthreads();
    for (int off = 1; off < SCAN_BS; off <<= 1) {
        int add = (t >= off) ? s[t - off] : 0;
        __syncthreads();
        s[t] += add;
        __syncthreads();
    }
    if (i < N) excl[i] = s[t] - v;   // exclusive
    if (t == SCAN_BS - 1) bsum[blockIdx.x] = s[t];
}

__global__ void scan2_kernel(int* __restrict__ bsum, int* __restrict__ total, int NB) {
    __shared__ int s[128];
    int t = threadIdx.x;
    int v = (t < NB) ? bsum[t] : 0;
    s[t] = v;
    __syncthreads();
    for (int off = 1; off < 128; off <<= 1) {
        int add = (t >= off) ? s[t - off] : 0;
        __syncthreads();
        s[t] += add;
        __syncthreads();
    }
    if (t < NB) bsum[t] = s[t] - v;  // exclusive
    if (t == 127) *total = s[127];
}

__global__ void scan3_kernel(int* __restrict__ excl, const int* __restrict__ bsum, int N) {
    int i = blockIdx.x * blockDim.x + threadIdx.x;
    if (i < N) excl[i] += bsum[i >> 10];   // SCAN_BS = 1024
}

// ---- scatter edges into padded CSR slots; col+val interleaved int2 ----
__global__ void scatter_kernel(const int* __restrict__ src, const int* __restrict__ dst,
                               const float* __restrict__ w, const int* __restrict__ row_start,
                               int* __restrict__ fill, int2* __restrict__ cv, int E) {
    int e = blockIdx.x * blockDim.x + threadIdx.x;
    if (e >= E) return;
    float wv = w[e];
    if (wv == 0.0f) return;
    int d = dst[e];
    int pos = row_start[d] + atomicAdd(&fill[d], 1);
    cv[pos] = make_int2(src[e], __float_as_int(wv));
}

// ---- prepB: arrange Bcat = [W2 | W1 | W0-W2] (FI x 3FO) into MFMA B-fragment layout ----
template <int FI, int FO>
__global__ void prepB_kernel(const float* __restrict__ W, unsigned short* __restrict__ Bfrag) {
    constexpr int NT = 3 * FO / 16;
    constexpr int NS = FI / 32;
    int id = blockIdx.x * blockDim.x + threadIdx.x;
    if (id >= NT * NS * 64) return;
    int lane = id & 63;
    int s = (id >> 6) % NS;
    int t = (id >> 6) / NS;
    int n = t * 16 + (lane & 15);
    int kbase = s * 32 + (lane >> 4) * 8;
    int sec = n / FO;        // 0 -> W2, 1 -> W1, 2 -> W0 - W2
    int nc  = n % FO;
    ushort8_t out;
#pragma unroll
    for (int j = 0; j < 8; j++) {
        int k = kbase + j;
        float v;
        if (sec == 0)      v = W[(size_t)(2 * FI + k) * FO + nc];
        else if (sec == 1) v = W[(size_t)(1 * FI + k) * FO + nc];
        else               v = W[(size_t)(0 * FI + k) * FO + nc]
                             - W[(size_t)(2 * FI + k) * FO + nc];
        out[j] = f2bf(v);
    }
    *(ushort8_t*)(Bfrag + (size_t)id * 8) = out;
}

// ---- MFMA gemm3: Ubf = bf16(x@W2), T = x@W1, S = x@(W0-W2) ----
// B fragments staged once into LDS (one barrier); per k-step each wave does
// 1 global A load + NT ds_reads + NT MFMAs (was 1+NT global loads -> latency-bound, R8 PMC).
template <int FI, int FO>
__global__ __launch_bounds__(256) void gemmM_kernel(
        const float* __restrict__ x, const unsigned short* __restrict__ Bfrag,
        float* __restrict__ T, float* __restrict__ S,
        unsigned short* __restrict__ Ubf, int N) {
    constexpr int NT = 3 * FO / 16;   // n-tiles
    constexpr int NS = FI / 32;       // k-steps
    constexpr int NFRAG = NT * NS;
    __shared__ ushort8_t bl[NFRAG * 64];

    const ushort8_t* bsrc = (const ushort8_t*)Bfrag;
    for (int q = threadIdx.x; q < NFRAG * 64; q += 256) bl[q] = bsrc[q];
    __syncthreads();

    const int lane = threadIdx.x & 63;
    const int wave = threadIdx.x >> 6;
    const int m0   = blockIdx.x * 64 + wave * 16;
    const int quad = lane >> 4;
    const int mrow = m0 + (lane & 15);

    floatx4_t acc[NT];
#pragma unroll
    for (int t = 0; t < NT; t++) acc[t] = (floatx4_t){0.f, 0.f, 0.f, 0.f};

#pragma unroll
    for (int s = 0; s < NS; s++) {
        bf16x8_t a;
        if (mrow < N) {
            const float* ap = x + (size_t)mrow * FI + s * 32 + quad * 8;
            float4 a0 = *(const float4*)(ap);
            float4 a1 = *(const float4*)(ap + 4);
            a[0] = (short)f2bf(a0.x); a[1] = (short)f2bf(a0.y);
            a[2] = (short)f2bf(a0.z); a[3] = (short)f2bf(a0.w);
            a[4] = (short)f2bf(a1.x); a[5] = (short)f2bf(a1.y);
            a[6] = (short)f2bf(a1.z); a[7] = (short)f2bf(a1.w);
        } else {
            a = (bf16x8_t){0, 0, 0, 0, 0, 0, 0, 0};
        }
#pragma unroll
        for (int t = 0; t < NT; t++) {
            bf16x8_t b = *(const bf16x8_t*)&bl[(t * NS + s) * 64 + lane];
            acc[t] = __builtin_amdgcn_mfma_f32_16x16x32_bf16(a, b, acc[t], 0, 0, 0);
        }
    }
    // C/D layout: col = lane&15, row = quad*4 + reg   [verified m89/m91]
#pragma unroll
    for (int t = 0; t < NT; t++) {
        int n   = t * 16 + (lane & 15);
        int sec = (t * 16) / FO;          // compile-time per t (FO multiple of 16)
        int nc  = n % FO;
#pragma unroll
        for (int r = 0; r < 4; r++) {
            int m = m0 + quad * 4 + r;
            if (m >= N) continue;
            float v = acc[t][r];
            size_t o = (size_t)m * FO + nc;
            if (sec == 0)      Ubf[o] = f2bf(v);
            else if (sec == 1) T[o] = v;
            else               S[o] = v;
        }
    }
}

// ---- propA8: Obf[i] = bf16( T[i] + 2 * sum_p val[p]*Ubf[col[p]] ) ----
// Thread per (row, 8-feature chunk), natural row order (streaming cv/T/writes;
// R8 showed degree-sorted indirection destroys this locality at a net loss).
template <int FO>
__global__ void propA8_kernel(const unsigned short* __restrict__ Ubf,
                              const float* __restrict__ T,
                              const int* __restrict__ rs, const int* __restrict__ cnt_n,
                              const int2* __restrict__ cv,
                              unsigned short* __restrict__ Obf, int N) {
    constexpr int PER = FO / 8;
    unsigned idx = blockIdx.x * blockDim.x + threadIdx.x;
    if (idx >= (unsigned)N * PER) return;
    int i = idx / PER;
    int c = (idx & (PER - 1)) * 8;
    int beg = rs[i], end = beg + cnt_n[i];
    float acc[8] = {0.f, 0.f, 0.f, 0.f, 0.f, 0.f, 0.f, 0.f};
    for (int p = beg; p < end; ++p) {
        int2 e = cv[p];
        float wv = __int_as_float(e.y);
        ushort8_t u = *(const ushort8_t*)(Ubf + (size_t)e.x * FO + c);
#pragma unroll
        for (int j = 0; j < 8; j++) acc[j] = fmaf(wv, bf2f(u[j]), acc[j]);
    }
    const float* tr = T + (size_t)i * FO + c;
    float4 t0 = *(const float4*)(tr);
    float4 t1 = *(const float4*)(tr + 4);
    const float ts[8] = {t0.x, t0.y, t0.z, t0.w, t1.x, t1.y, t1.z, t1.w};
    ushort8_t o;
#pragma unroll
    for (int j = 0; j < 8; j++) o[j] = f2bf(ts[j] + 2.f * acc[j]);
    *(ushort8_t*)(Obf + (size_t)i * FO + c) = o;
}

// ---- propC8: h[i] = leaky_relu(BN(S[i] + sum_p val[p]*Bbf[col[p]] + b))  (h may == S) ----
template <int FO>
__global__ void propC8_kernel(const unsigned short* __restrict__ Bbf,
                              const float* __restrict__ S,
                              const int* __restrict__ rs, const int* __restrict__ cnt_n,
                              const int2* __restrict__ cv,
                              const float* __restrict__ b, const float* __restrict__ g,
                              const float* __restrict__ be, const float* __restrict__ m,
                              const float* __restrict__ vv, float* __restrict__ h, int N) {
    constexpr int PER = FO / 8;
    unsigned idx = blockIdx.x * blockDim.x + threadIdx.x;
    if (idx >= (unsigned)N * PER) return;
    int i = idx / PER;
    int c = (idx & (PER - 1)) * 8;
    int beg = rs[i], end = beg + cnt_n[i];
    float acc[8] = {0.f, 0.f, 0.f, 0.f, 0.f, 0.f, 0.f, 0.f};
    for (int p = beg; p < end; ++p) {
        int2 e = cv[p];
        float wv = __int_as_float(e.y);
        ushort8_t u = *(const ushort8_t*)(Bbf + (size_t)e.x * FO + c);
#pragma unroll
        for (int j = 0; j < 8; j++) acc[j] = fmaf(wv, bf2f(u[j]), acc[j]);
    }
    const float* sr = S + (size_t)i * FO + c;
    float4 s0 = *(const float4*)(sr);
    float4 s1 = *(const float4*)(sr + 4);
    const float ss[8] = {s0.x, s0.y, s0.z, s0.w, s1.x, s1.y, s1.z, s1.w};
    float out[8];
#pragma unroll
    for (int j = 0; j < 8; j++) {
        int f = c + j;
        float A = g[f] * rsqrtf(vv[f] + BN_EPS);
        float B = be[f] - (m[f] - b[f]) * A;
        float y = (ss[j] + acc[j]) * A + B;
        out[j] = y > 0.0f ? y : 0.01f * y;
    }
    float* hr = h + (size_t)i * FO + c;
    *(float4*)(hr)     = make_float4(out[0], out[1], out[2], out[3]);
    *(float4*)(hr + 4) = make_float4(out[4], out[5], out[6], out[7]);
}

// ---- mean pool v3: thread = (node-lane, feature-quad); float4 loads ----
__global__ __launch_bounds__(256) void pool3_kernel(
        const float* __restrict__ h, const int* __restrict__ batch,
        float* __restrict__ pool, float* __restrict__ cnt, int N) {
    __shared__ float sp[NG * 16];
    __shared__ float sc[NG];
    int t = threadIdx.x;
    for (int i = t; i < NG * 16; i += 256) sp[i] = 0.f;
    for (int i = t; i < NG; i += 256) sc[i] = 0.f;
    __syncthreads();
    const int f4 = (t & 3) * 4;      // feature quad
    const int nl = t >> 2;           // node lane 0..63
    const int base = blockIdx.x * PNPB;
    const int nEnd = min(base + PNPB, N);
    float4 acc = make_float4(0.f, 0.f, 0.f, 0.f);
    float cacc = 0.f;
    int gcur = -1;
    for (int n = base + nl; n < nEnd; n += 64) {
        int g = batch[n];
        if (g != gcur) {
            if (gcur >= 0) {
                atomicAdd(&sp[gcur * 16 + f4 + 0], acc.x);
                atomicAdd(&sp[gcur * 16 + f4 + 1], acc.y);
                atomicAdd(&sp[gcur * 16 + f4 + 2], acc.z);
                atomicAdd(&sp[gcur * 16 + f4 + 3], acc.w);
                if (f4 == 0) atomicAdd(&sc[gcur], cacc);
            }
            gcur = g; acc = make_float4(0.f, 0.f, 0.f, 0.f); cacc = 0.f;
        }
        float4 hv = *(const float4*)(h + (size_t)n * 16 + f4);
        acc.x += hv.x; acc.y += hv.y; acc.z += hv.z; acc.w += hv.w;
        cacc += 1.f;
    }
    if (gcur >= 0) {
        atomicAdd(&sp[gcur * 16 + f4 + 0], acc.x);
        atomicAdd(&sp[gcur * 16 + f4 + 1], acc.y);
        atomicAdd(&sp[gcur * 16 + f4 + 2], acc.z);
        atomicAdd(&sp[gcur * 16 + f4 + 3], acc.w);
        if (f4 == 0) atomicAdd(&sc[gcur], cacc);
    }
    __syncthreads();
    for (int i = t; i < NG * 16; i += 256)
        if (sp[i] != 0.f) unsafeAtomicAdd(&pool[i], sp[i]);
    for (int i = t; i < NG; i += 256)
        if (sc[i] != 0.f) unsafeAtomicAdd(&cnt[i], sc[i]);
}

// ---------------- final linear head ----------------
__global__ void final_kernel(const float* __restrict__ pool, const float* __restrict__ cnt,
                             const float* __restrict__ lw, const float* __restrict__ lb,
                             float* __restrict__ out) {
    int idx = threadIdx.x;
    if (idx >= NG * 2) return;
    int g = idx >> 1;
    int c = idx & 1;
    float inv = 1.0f / fmaxf(cnt[g], 1.0f);
    float acc = 0.0f;
#pragma unroll
    for (int f = 0; f < 16; f++) acc += pool[g * 16 + f] * lw[c * 16 + f];
    out[idx] = acc * inv + lb[c];
}

extern "C" void kernel_launch(void* const* d_in, const int* in_sizes, int n_in,
                              void* d_out, int out_size, void* d_ws, size_t ws_size,
                              hipStream_t stream) {
    const float* x    = (const float*)d_in[0];
    const int*   ei   = (const int*)d_in[1];
    const int*   batch= (const int*)d_in[2];
    const float* W1 = (const float*)d_in[3];
    const float* b1 = (const float*)d_in[4];
    const float* g1 = (const float*)d_in[5];
    const float* be1= (const float*)d_in[6];
    const float* m1 = (const float*)d_in[7];
    const float* v1 = (const float*)d_in[8];
    const float* W2 = (const float*)d_in[9];
    const float* b2 = (const float*)d_in[10];
    const float* g2 = (const float*)d_in[11];
    const float* be2= (const float*)d_in[12];
    const float* m2 = (const float*)d_in[13];
    const float* v2 = (const float*)d_in[14];
    const float* W3 = (const float*)d_in[15];
    const float* b3 = (const float*)d_in[16];
    const float* g3 = (const float*)d_in[17];
    const float* be3= (const float*)d_in[18];
    const float* m3 = (const float*)d_in[19];
    const float* v3 = (const float*)d_in[20];
    const float* lw = (const float*)d_in[21];
    const float* lb = (const float*)d_in[22];

    const int* src = ei;            // edge_index[0]
    const int* dst = ei + NE;       // edge_index[1]

    float* ws = (float*)d_ws;
    // ---- workspace layout (4-byte units, 16B-aligned) ----
    size_t off = 0;
    float* deg   = ws + off; off += NN;
    int*   cnt_n = (int*)(ws + off); off += NN;
    int*   fill  = (int*)(ws + off); off += NN;
    float* pool  = ws + off; off += NG * 16;
    float* cnt   = ws + off; off += NG;
    size_t zero_bytes = off * sizeof(float);       // one memset covers all of the above
    float* w     = ws + off; off += NE;
    int*   rs    = (int*)(ws + off); off += NN + 4;  // padded row_start [N+1]
    int2*  cv    = (int2*)(ws + off); off += 2 * (size_t)MAXSLOT;  // interleaved {col,val}
    int*   bsum  = (int*)(ws + off); off += 128;
    float* A    = ws + off; off += (size_t)NN * 64;          // T buffers; tail reused as C16
    float* Bb   = ws + off; off += (size_t)NN * 64;          // S1 / h1
    float* D    = ws + off; off += (size_t)NN * 32;          // S2 / h2
    unsigned short* Ubf  = (unsigned short*)(ws + off); off += (size_t)NN * 32;  // NN*64 bf16
    unsigned short* Bbbf = (unsigned short*)(ws + off); off += (size_t)NN * 32;  // NN*64 bf16
    // C16 (S3/h3, NN*16 floats) overlays A's tail: layer-3 T only uses A[0:NN*16]
    float* C16 = A + (size_t)NN * 16;

    // B-fragment buffers overlay `deg` (dead after wgt_hist): ~65 KB << 400 KB
    unsigned short* Bf1 = (unsigned short*)deg;              // 12*4*64*8 = 24576 bf16
    unsigned short* Bf2 = Bf1 + 12 * 4 * 64 * 8;             //  6*2*64*8 =  6144 bf16
    unsigned short* Bf3 = Bf2 + 6 * 2 * 64 * 8;              //  3*1*64*8 =  1536 bf16

    hipMemsetAsync(ws, 0, zero_bytes, stream);

    // ---- edge weights + CSR build ----
    deg_kernel<<<cdiv(NE, BS), BS, 0, stream>>>(src, dst, deg, NE);
    wgt_hist_kernel<<<cdiv(NE, BS), BS, 0, stream>>>(src, dst, deg, w, cnt_n, NE);
    // deg now dead -> overlay Bfrag buffers
    prepB_kernel<128, 64><<<cdiv(12 * 4 * 64, BS), BS, 0, stream>>>(W1, Bf1);
    prepB_kernel<64, 32><<<cdiv(6 * 2 * 64, BS), BS, 0, stream>>>(W2, Bf2);
    prepB_kernel<32, 16><<<cdiv(3 * 1 * 64, BS), BS, 0, stream>>>(W3, Bf3);
    scan1_kernel<<<NB_SCAN, SCAN_BS, 0, stream>>>(cnt_n, rs, bsum, NN);
    scan2_kernel<<<1, 128, 0, stream>>>(bsum, rs + NN, NB_SCAN);
    scan3_kernel<<<cdiv(NN, BS), BS, 0, stream>>>(rs, bsum, NN);
    scatter_kernel<<<cdiv(NE, BS), BS, 0, stream>>>(src, dst, w, rs, fill, cv, NE);

    // ---- layer 1: 128 -> 64 ----
    gemmM_kernel<128, 64><<<cdiv(NN, 64), 256, 0, stream>>>(x, Bf1, A, Bb, Ubf, NN);
    propA8_kernel<64><<<cdiv((long long)NN * 8, BS), BS, 0, stream>>>(Ubf, A, rs, cnt_n, cv, Bbbf, NN);
    propC8_kernel<64><<<cdiv((long long)NN * 8, BS), BS, 0, stream>>>(Bbbf, Bb, rs, cnt_n, cv,
                                                                      b1, g1, be1, m1, v1, Bb, NN);
    // ---- layer 2: 64 -> 32 ----
    gemmM_kernel<64, 32><<<cdiv(NN, 64), 256, 0, stream>>>(Bb, Bf2, A, D, Ubf, NN);
    propA8_kernel<32><<<cdiv((long long)NN * 4, BS), BS, 0, stream>>>(Ubf, A, rs, cnt_n, cv, Bbbf, NN);
    propC8_kernel<32><<<cdiv((long long)NN * 4, BS), BS, 0, stream>>>(Bbbf, D, rs, cnt_n, cv,
                                                                      b2, g2, be2, m2, v2, D, NN);
    // ---- layer 3: 32 -> 16 ----
    gemmM_kernel<32, 16><<<cdiv(NN, 64), 256, 0, stream>>>(D, Bf3, A, C16, Ubf, NN);
    propA8_kernel<16><<<cdiv((long long)NN * 2, BS), BS, 0, stream>>>(Ubf, A, rs, cnt_n, cv, Bbbf, NN);
    propC8_kernel<16><<<cdiv((long long)NN * 2, BS), BS, 0, stream>>>(Bbbf, C16, rs, cnt_n, cv,
                                                                      b3, g3, be3, m3, v3, C16, NN);
    // ---- pool + head ----
    pool3_kernel<<<cdiv(NN, PNPB), 256, 0, stream>>>(C16, batch, pool, cnt, NN);
    final_kernel<<<1, 128, 0, stream>>>(pool, cnt, lw, lb, (float*)d_out);
}

// Round 10
// 411.466 us; speedup vs baseline: 1.1891x; 1.0865x over previous
//
#include <hip/hip_runtime.h>
#include <hip/hip_bf16.h>

// Problem constants (match reference)
#define NN 100000   // nodes
#define NE 640000   // edges
#define NG 64       // graphs
#define BN_EPS 1e-5f

#define BS 256      // block size
#define SCAN_BS 1024
#define NB_SCAN ((NN + SCAN_BS - 1) / SCAN_BS)   // 98
#define PNPB 256    // nodes per block in pool
#define MAXSLOT (NE + 7 * NN)   // padded CSR capacity (pad-to-8 per row)

typedef __attribute__((ext_vector_type(8))) unsigned short ushort8_t;
typedef __attribute__((ext_vector_type(8))) short bf16x8_t;    // MFMA A/B frag (4 VGPR)
typedef __attribute__((ext_vector_type(4))) float floatx4_t;   // MFMA C/D frag

static inline int cdiv(long long a, int b) { return (int)((a + b - 1) / b); }

__device__ __forceinline__ float bf2f(unsigned short u) {
    union { unsigned int i; float f; } c; c.i = ((unsigned int)u) << 16; return c.f;
}
__device__ __forceinline__ unsigned short f2bf(float f) {   // RNE
    unsigned int u = __float_as_uint(f);
    u += 0x7fffu + ((u >> 16) & 1u);
    return (unsigned short)(u >> 16);
}

// ---- hist: deg_i[s]++ (out-degree as src) and cnt_n[d]++ per non-loop edge ----
// Replaces old deg_kernel + the histogram half of wgt_hist (one edge pass fewer).
__global__ void hist_kernel(const int* __restrict__ src, const int* __restrict__ dst,
                            int* __restrict__ deg_i, int* __restrict__ cnt_n, int E) {
    int e0 = (blockIdx.x * blockDim.x + threadIdx.x) * 2;
#pragma unroll
    for (int q = 0; q < 2; q++) {
        int e = e0 + q;
        if (e < E) {
            int s = src[e], d = dst[e];
            if (s != d) { atomicAdd(&deg_i[s], 1); atomicAdd(&cnt_n[d], 1); }
        }
    }
}

// ---- 3-kernel -> 2-kernel exclusive scan of PADDED counts (ceil8) -> rs (+bsum inline) ----
__global__ void scan1_kernel(const int* __restrict__ cnt, int* __restrict__ excl,
                             int* __restrict__ bsum, int N) {
    __shared__ int s[SCAN_BS];
    int t = threadIdx.x;
    int i = blockIdx.x * SCAN_BS + t;
    int v = (i < N) ? ((cnt[i] + 7) & ~7) : 0;
    s[t] = v;
    __syncthreads();
    for (int off = 1; off < SCAN_BS; off <<= 1) {
        int add = (t >= off) ? s[t - off] : 0;
        __syncthreads();
        s[t] += add;
        __syncthreads();
    }
    if (i < N) excl[i] = s[t] - v;   // exclusive within block; consumers add bsum[i>>10]
    if (t == SCAN_BS - 1) bsum[blockIdx.x] = s[t];
}

__global__ void scan2_kernel(int* __restrict__ bsum, int NB) {
    __shared__ int s[128];
    int t = threadIdx.x;
    int v = (t < NB) ? bsum[t] : 0;
    s[t] = v;
    __syncthreads();
    for (int off = 1; off < 128; off <<= 1) {
        int add = (t >= off) ? s[t - off] : 0;
        __syncthreads();
        s[t] += add;
        __syncthreads();
    }
    if (t < NB) bsum[t] = s[t] - v;  // exclusive
}

// ---- scatter + inline weight: cv[pos] = {src, -dinv[s]*dinv[d]} (w array eliminated) ----
__global__ void scatter_wgt_kernel(const int* __restrict__ src, const int* __restrict__ dst,
                                   const int* __restrict__ deg_i, const int* __restrict__ rs,
                                   const int* __restrict__ bsum, int* __restrict__ fill,
                                   int2* __restrict__ cv, int E) {
    int e0 = (blockIdx.x * blockDim.x + threadIdx.x) * 2;
#pragma unroll
    for (int q = 0; q < 2; q++) {
        int e = e0 + q;
        if (e < E) {
            int s = src[e], d = dst[e];
            if (s != d) {
                int ds = deg_i[s], dd = deg_i[d];   // ds >= 1 guaranteed (edge e itself)
                float wv = (dd > 0) ? -rsqrtf((float)ds) * rsqrtf((float)dd) : 0.0f;
                int pos = rs[d] + bsum[d >> 10] + atomicAdd(&fill[d], 1);
                cv[pos] = make_int2(s, __float_as_int(wv));
            }
        }
    }
}

// ---- prepB (merged): Bcat = [W2 | W1 | W0-W2] (FI x 3FO) in MFMA B-fragment layout ----
template <int FI, int FO>
__device__ __forceinline__ void prep_one(const float* __restrict__ W,
                                         unsigned short* __restrict__ Bfrag, int id) {
    constexpr int NS = FI / 32;
    int lane = id & 63;
    int s = (id >> 6) % NS;
    int t = (id >> 6) / NS;
    int n = t * 16 + (lane & 15);
    int kbase = s * 32 + (lane >> 4) * 8;
    int sec = n / FO;        // 0 -> W2, 1 -> W1, 2 -> W0 - W2
    int nc  = n % FO;
    ushort8_t out;
#pragma unroll
    for (int j = 0; j < 8; j++) {
        int k = kbase + j;
        float v;
        if (sec == 0)      v = W[(size_t)(2 * FI + k) * FO + nc];
        else if (sec == 1) v = W[(size_t)(1 * FI + k) * FO + nc];
        else               v = W[(size_t)(0 * FI + k) * FO + nc]
                             - W[(size_t)(2 * FI + k) * FO + nc];
        out[j] = f2bf(v);
    }
    *(ushort8_t*)(Bfrag + (size_t)id * 8) = out;
}

__global__ void prepB_all_kernel(const float* __restrict__ W1, const float* __restrict__ W2,
                                 const float* __restrict__ W3,
                                 unsigned short* __restrict__ Bf1,
                                 unsigned short* __restrict__ Bf2,
                                 unsigned short* __restrict__ Bf3) {
    int id = blockIdx.x * blockDim.x + threadIdx.x;
    if (id < 3072)      prep_one<128, 64>(W1, Bf1, id);            // 12*4*64
    else if (id < 3840) prep_one<64, 32>(W2, Bf2, id - 3072);      //  6*2*64
    else if (id < 4032) prep_one<32, 16>(W3, Bf3, id - 3840);      //  3*1*64
}

// ---- MFMA gemm3: Ubf = bf16(x@W2), Tbf = bf16(x@W1), S = x@(W0-W2) fp32 ----
// B fragments staged once into LDS (single barrier). T stored bf16: propA rounds
// its output to bf16 anyway, so T's extra rounding is second-order.
template <int FI, int FO>
__global__ __launch_bounds__(256) void gemmM_kernel(
        const float* __restrict__ x, const unsigned short* __restrict__ Bfrag,
        unsigned short* __restrict__ Tbf, float* __restrict__ S,
        unsigned short* __restrict__ Ubf, int N) {
    constexpr int NT = 3 * FO / 16;   // n-tiles
    constexpr int NS = FI / 32;       // k-steps
    constexpr int NFRAG = NT * NS;
    __shared__ ushort8_t bl[NFRAG * 64];

    const ushort8_t* bsrc = (const ushort8_t*)Bfrag;
    for (int q = threadIdx.x; q < NFRAG * 64; q += 256) bl[q] = bsrc[q];
    __syncthreads();

    const int lane = threadIdx.x & 63;
    const int wave = threadIdx.x >> 6;
    const int m0   = blockIdx.x * 64 + wave * 16;
    const int quad = lane >> 4;
    const int mrow = m0 + (lane & 15);

    floatx4_t acc[NT];
#pragma unroll
    for (int t = 0; t < NT; t++) acc[t] = (floatx4_t){0.f, 0.f, 0.f, 0.f};

#pragma unroll
    for (int s = 0; s < NS; s++) {
        bf16x8_t a;
        if (mrow < N) {
            const float* ap = x + (size_t)mrow * FI + s * 32 + quad * 8;
            float4 a0 = *(const float4*)(ap);
            float4 a1 = *(const float4*)(ap + 4);
            a[0] = (short)f2bf(a0.x); a[1] = (short)f2bf(a0.y);
            a[2] = (short)f2bf(a0.z); a[3] = (short)f2bf(a0.w);
            a[4] = (short)f2bf(a1.x); a[5] = (short)f2bf(a1.y);
            a[6] = (short)f2bf(a1.z); a[7] = (short)f2bf(a1.w);
        } else {
            a = (bf16x8_t){0, 0, 0, 0, 0, 0, 0, 0};
        }
#pragma unroll
        for (int t = 0; t < NT; t++) {
            bf16x8_t b = *(const bf16x8_t*)&bl[(t * NS + s) * 64 + lane];
            acc[t] = __builtin_amdgcn_mfma_f32_16x16x32_bf16(a, b, acc[t], 0, 0, 0);
        }
    }
    // C/D layout: col = lane&15, row = quad*4 + reg   [verified m89/m91]
#pragma unroll
    for (int t = 0; t < NT; t++) {
        int n   = t * 16 + (lane & 15);
        int sec = (t * 16) / FO;          // compile-time per t (FO multiple of 16)
        int nc  = n % FO;
#pragma unroll
        for (int r = 0; r < 4; r++) {
            int m = m0 + quad * 4 + r;
            if (m >= N) continue;
            float v = acc[t][r];
            size_t o = (size_t)m * FO + nc;
            if (sec == 0)      Ubf[o] = f2bf(v);
            else if (sec == 1) Tbf[o] = f2bf(v);
            else               S[o] = v;
        }
    }
}

// ---- propA8: Obf[i] = bf16( T[i] + 2 * sum_p val[p]*Ubf[col[p]] ) ----
// Thread per (row, 8-feature chunk), natural row order (streaming locality; R8
// showed degree-sorted indirection loses). beg adds bsum inline (scan3 removed).
template <int FO>
__global__ void propA8_kernel(const unsigned short* __restrict__ Ubf,
                              const unsigned short* __restrict__ Tbf,
                              const int* __restrict__ rs, const int* __restrict__ bsum,
                              const int* __restrict__ cnt_n, const int2* __restrict__ cv,
                              unsigned short* __restrict__ Obf, int N) {
    constexpr int PER = FO / 8;
    unsigned idx = blockIdx.x * blockDim.x + threadIdx.x;
    if (idx >= (unsigned)N * PER) return;
    int i = idx / PER;
    int c = (idx & (PER - 1)) * 8;
    int beg = rs[i] + bsum[i >> 10];
    int end = beg + cnt_n[i];
    float acc[8] = {0.f, 0.f, 0.f, 0.f, 0.f, 0.f, 0.f, 0.f};
    for (int p = beg; p < end; ++p) {
        int2 e = cv[p];
        float wv = __int_as_float(e.y);
        ushort8_t u = *(const ushort8_t*)(Ubf + (size_t)e.x * FO + c);
#pragma unroll
        for (int j = 0; j < 8; j++) acc[j] = fmaf(wv, bf2f(u[j]), acc[j]);
    }
    ushort8_t tv = *(const ushort8_t*)(Tbf + (size_t)i * FO + c);
    ushort8_t o;
#pragma unroll
    for (int j = 0; j < 8; j++) o[j] = f2bf(bf2f(tv[j]) + 2.f * acc[j]);
    *(ushort8_t*)(Obf + (size_t)i * FO + c) = o;
}

// ---- propC8: h[i] = leaky_relu(BN(S[i] + sum_p val[p]*Bbf[col[p]] + b))  (h may == S) ----
template <int FO>
__global__ void propC8_kernel(const unsigned short* __restrict__ Bbf,
                              const float* __restrict__ S,
                              const int* __restrict__ rs, const int* __restrict__ bsum,
                              const int* __restrict__ cnt_n, const int2* __restrict__ cv,
                              const float* __restrict__ b, const float* __restrict__ g,
                              const float* __restrict__ be, const float* __restrict__ m,
                              const float* __restrict__ vv, float* __restrict__ h, int N) {
    constexpr int PER = FO / 8;
    unsigned idx = blockIdx.x * blockDim.x + threadIdx.x;
    if (idx >= (unsigned)N * PER) return;
    int i = idx / PER;
    int c = (idx & (PER - 1)) * 8;
    int beg = rs[i] + bsum[i >> 10];
    int end = beg + cnt_n[i];
    float acc[8] = {0.f, 0.f, 0.f, 0.f, 0.f, 0.f, 0.f, 0.f};
    for (int p = beg; p < end; ++p) {
        int2 e = cv[p];
        float wv = __int_as_float(e.y);
        ushort8_t u = *(const ushort8_t*)(Bbf + (size_t)e.x * FO + c);
#pragma unroll
        for (int j = 0; j < 8; j++) acc[j] = fmaf(wv, bf2f(u[j]), acc[j]);
    }
    const float* sr = S + (size_t)i * FO + c;
    float4 s0 = *(const float4*)(sr);
    float4 s1 = *(const float4*)(sr + 4);
    const float ss[8] = {s0.x, s0.y, s0.z, s0.w, s1.x, s1.y, s1.z, s1.w};
    float out[8];
#pragma unroll
    for (int j = 0; j < 8; j++) {
        int f = c + j;
        float A = g[f] * rsqrtf(vv[f] + BN_EPS);
        float B = be[f] - (m[f] - b[f]) * A;
        float y = (ss[j] + acc[j]) * A + B;
        out[j] = y > 0.0f ? y : 0.01f * y;
    }
    float* hr = h + (size_t)i * FO + c;
    *(float4*)(hr)     = make_float4(out[0], out[1], out[2], out[3]);
    *(float4*)(hr + 4) = make_float4(out[4], out[5], out[6], out[7]);
}

// ---- mean pool v3: thread = (node-lane, feature-quad); float4 loads ----
__global__ __launch_bounds__(256) void pool3_kernel(
        const float* __restrict__ h, const int* __restrict__ batch,
        float* __restrict__ pool, float* __restrict__ cnt, int N) {
    __shared__ float sp[NG * 16];
    __shared__ float sc[NG];
    int t = threadIdx.x;
    for (int i = t; i < NG * 16; i += 256) sp[i] = 0.f;
    for (int i = t; i < NG; i += 256) sc[i] = 0.f;
    __syncthreads();
    const int f4 = (t & 3) * 4;      // feature quad
    const int nl = t >> 2;           // node lane 0..63
    const int base = blockIdx.x * PNPB;
    const int nEnd = min(base + PNPB, N);
    float4 acc = make_float4(0.f, 0.f, 0.f, 0.f);
    float cacc = 0.f;
    int gcur = -1;
    for (int n = base + nl; n < nEnd; n += 64) {
        int g = batch[n];
        if (g != gcur) {
            if (gcur >= 0) {
                atomicAdd(&sp[gcur * 16 + f4 + 0], acc.x);
                atomicAdd(&sp[gcur * 16 + f4 + 1], acc.y);
                atomicAdd(&sp[gcur * 16 + f4 + 2], acc.z);
                atomicAdd(&sp[gcur * 16 + f4 + 3], acc.w);
                if (f4 == 0) atomicAdd(&sc[gcur], cacc);
            }
            gcur = g; acc = make_float4(0.f, 0.f, 0.f, 0.f); cacc = 0.f;
        }
        float4 hv = *(const float4*)(h + (size_t)n * 16 + f4);
        acc.x += hv.x; acc.y += hv.y; acc.z += hv.z; acc.w += hv.w;
        cacc += 1.f;
    }
    if (gcur >= 0) {
        atomicAdd(&sp[gcur * 16 + f4 + 0], acc.x);
        atomicAdd(&sp[gcur * 16 + f4 + 1], acc.y);
        atomicAdd(&sp[gcur * 16 + f4 + 2], acc.z);
        atomicAdd(&sp[gcur * 16 + f4 + 3], acc.w);
        if (f4 == 0) atomicAdd(&sc[gcur], cacc);
    }
    __syncthreads();
    for (int i = t; i < NG * 16; i += 256)
        if (sp[i] != 0.f) unsafeAtomicAdd(&pool[i], sp[i]);
    for (int i = t; i < NG; i += 256)
        if (sc[i] != 0.f) unsafeAtomicAdd(&cnt[i], sc[i]);
}

// ---------------- final linear head ----------------
__global__ void final_kernel(const float* __restrict__ pool, const float* __restrict__ cnt,
                             const float* __restrict__ lw, const float* __restrict__ lb,
                             float* __restrict__ out) {
    int idx = threadIdx.x;
    if (idx >= NG * 2) return;
    int g = idx >> 1;
    int c = idx & 1;
    float inv = 1.0f / fmaxf(cnt[g], 1.0f);
    float acc = 0.0f;
#pragma unroll
    for (int f = 0; f < 16; f++) acc += pool[g * 16 + f] * lw[c * 16 + f];
    out[idx] = acc * inv + lb[c];
}

extern "C" void kernel_launch(void* const* d_in, const int* in_sizes, int n_in,
                              void* d_out, int out_size, void* d_ws, size_t ws_size,
                              hipStream_t stream) {
    const float* x    = (const float*)d_in[0];
    const int*   ei   = (const int*)d_in[1];
    const int*   batch= (const int*)d_in[2];
    const float* W1 = (const float*)d_in[3];
    const float* b1 = (const float*)d_in[4];
    const float* g1 = (const float*)d_in[5];
    const float* be1= (const float*)d_in[6];
    const float* m1 = (const float*)d_in[7];
    const float* v1 = (const float*)d_in[8];
    const float* W2 = (const float*)d_in[9];
    const float* b2 = (const float*)d_in[10];
    const float* g2 = (const float*)d_in[11];
    const float* be2= (const float*)d_in[12];
    const float* m2 = (const float*)d_in[13];
    const float* v2 = (const float*)d_in[14];
    const float* W3 = (const float*)d_in[15];
    const float* b3 = (const float*)d_in[16];
    const float* g3 = (const float*)d_in[17];
    const float* be3= (const float*)d_in[18];
    const float* m3 = (const float*)d_in[19];
    const float* v3 = (const float*)d_in[20];
    const float* lw = (const float*)d_in[21];
    const float* lb = (const float*)d_in[22];

    const int* src = ei;            // edge_index[0]
    const int* dst = ei + NE;       // edge_index[1]

    float* ws = (float*)d_ws;
    // ---- workspace layout (4-byte units, 16B-aligned; ~95.6 MB total) ----
    size_t off = 0;
    int*   deg_i = (int*)(ws + off); off += NN;
    int*   cnt_n = (int*)(ws + off); off += NN;
    int*   fill  = (int*)(ws + off); off += NN;
    float* pool  = ws + off; off += NG * 16;
    float* cnt   = ws + off; off += NG;
    size_t zero_bytes = off * sizeof(float);       // one memset covers all of the above
    int*   rs    = (int*)(ws + off); off += NN + 4;  // padded per-1024-block excl scan
    int*   bsum  = (int*)(ws + off); off += 128;
    int2*  cv    = (int2*)(ws + off); off += 2 * (size_t)MAXSLOT;  // interleaved {col,val}
    unsigned short* Tbf = (unsigned short*)(ws + off); off += (size_t)NN * 32;  // NN*64 bf16
    float* Bb   = ws + off; off += (size_t)NN * 64;          // S1 / h1 (fp32)
    float* D    = ws + off; off += (size_t)NN * 32;          // S2 / h2
    float* C16  = ws + off; off += (size_t)NN * 16;          // S3 / h3
    unsigned short* Ubf  = (unsigned short*)(ws + off); off += (size_t)NN * 32;  // NN*64 bf16
    unsigned short* Bbbf = (unsigned short*)(ws + off); off += (size_t)NN * 32;  // NN*64 bf16
    unsigned short* Bf1  = (unsigned short*)(ws + off); off += 12288;  // 24576 bf16
    unsigned short* Bf2  = (unsigned short*)(ws + off); off += 3072;   //  6144 bf16
    unsigned short* Bf3  = (unsigned short*)(ws + off); off += 768;    //  1536 bf16

    hipMemsetAsync(ws, 0, zero_bytes, stream);

    // ---- CSR build: hist -> scan(2) -> scatter+weight (w array & wgt pass eliminated) ----
    hist_kernel<<<cdiv(NE, 2 * BS), BS, 0, stream>>>(src, dst, deg_i, cnt_n, NE);
    prepB_all_kernel<<<16, BS, 0, stream>>>(W1, W2, W3, Bf1, Bf2, Bf3);
    scan1_kernel<<<NB_SCAN, SCAN_BS, 0, stream>>>(cnt_n, rs, bsum, NN);
    scan2_kernel<<<1, 128, 0, stream>>>(bsum, NB_SCAN);
    scatter_wgt_kernel<<<cdiv(NE, 2 * BS), BS, 0, stream>>>(src, dst, deg_i, rs, bsum,
                                                            fill, cv, NE);

    // ---- layer 1: 128 -> 64 ----
    gemmM_kernel<128, 64><<<cdiv(NN, 64), 256, 0, stream>>>(x, Bf1, Tbf, Bb, Ubf, NN);
    propA8_kernel<64><<<cdiv((long long)NN * 8, BS), BS, 0, stream>>>(Ubf, Tbf, rs, bsum,
                                                                      cnt_n, cv, Bbbf, NN);
    propC8_kernel<64><<<cdiv((long long)NN * 8, BS), BS, 0, stream>>>(Bbbf, Bb, rs, bsum,
                                                                      cnt_n, cv,
                                                                      b1, g1, be1, m1, v1, Bb, NN);
    // ---- layer 2: 64 -> 32 ----
    gemmM_kernel<64, 32><<<cdiv(NN, 64), 256, 0, stream>>>(Bb, Bf2, Tbf, D, Ubf, NN);
    propA8_kernel<32><<<cdiv((long long)NN * 4, BS), BS, 0, stream>>>(Ubf, Tbf, rs, bsum,
                                                                      cnt_n, cv, Bbbf, NN);
    propC8_kernel<32><<<cdiv((long long)NN * 4, BS), BS, 0, stream>>>(Bbbf, D, rs, bsum,
                                                                      cnt_n, cv,
                                                                      b2, g2, be2, m2, v2, D, NN);
    // ---- layer 3: 32 -> 16 ----
    gemmM_kernel<32, 16><<<cdiv(NN, 64), 256, 0, stream>>>(D, Bf3, Tbf, C16, Ubf, NN);
    propA8_kernel<16><<<cdiv((long long)NN * 2, BS), BS, 0, stream>>>(Ubf, Tbf, rs, bsum,
                                                                      cnt_n, cv, Bbbf, NN);
    propC8_kernel<16><<<cdiv((long long)NN * 2, BS), BS, 0, stream>>>(Bbbf, C16, rs, bsum,
                                                                      cnt_n, cv,
                                                                      b3, g3, be3, m3, v3, C16, NN);
    // ---- pool + head ----
    pool3_kernel<<<cdiv(NN, PNPB), 256, 0, stream>>>(C16, batch, pool, cnt, NN);
    final_kernel<<<1, 128, 0, stream>>>(pool, cnt, lw, lb, (float*)d_out);
}

// Round 11
// 410.554 us; speedup vs baseline: 1.1918x; 1.0022x over previous
//
#include <hip/hip_runtime.h>
#include <hip/hip_bf16.h>

// Problem constants (match reference)
#define NN 100000   // nodes
#define NE 640000   // edges
#define NG 64       // graphs
#define BN_EPS 1e-5f

#define BS 256      // block size
#define SCAN_BS 1024
#define NB_SCAN ((NN + SCAN_BS - 1) / SCAN_BS)   // 98
#define PNPB 256    // nodes per block in pool
#define MAXSLOT (NE + 7 * NN)   // padded CSR capacity (pad-to-8 per row)

typedef __attribute__((ext_vector_type(8))) unsigned short ushort8_t;
typedef __attribute__((ext_vector_type(8))) short bf16x8_t;    // MFMA A/B frag (4 VGPR)
typedef __attribute__((ext_vector_type(4))) float floatx4_t;   // MFMA C/D frag

static inline int cdiv(long long a, int b) { return (int)((a + b - 1) / b); }

__device__ __forceinline__ float bf2f(unsigned short u) {
    union { unsigned int i; float f; } c; c.i = ((unsigned int)u) << 16; return c.f;
}
__device__ __forceinline__ unsigned short f2bf(float f) {   // RNE
    unsigned int u = __float_as_uint(f);
    u += 0x7fffu + ((u >> 16) & 1u);
    return (unsigned short)(u >> 16);
}

// ---- hist8: XCD-sharded histograms. blockIdx&7 picks a private copy so atomic
// lines stay dirty in one XCD's L2 (R10 PMC: shared-copy version wrote 39.9 MB
// of HBM line-bounce traffic for 800 KB of counters). ----
__global__ void hist_kernel(const int* __restrict__ src, const int* __restrict__ dst,
                            int* __restrict__ deg8, int* __restrict__ cnt8, int E) {
    int slot = blockIdx.x & 7;
    int* dg = deg8 + (size_t)slot * NN;
    int* cn = cnt8 + (size_t)slot * NN;
    int e0 = (blockIdx.x * blockDim.x + threadIdx.x) * 2;
#pragma unroll
    for (int q = 0; q < 2; q++) {
        int e = e0 + q;
        if (e < E) {
            int s = src[e], d = dst[e];
            if (s != d) { atomicAdd(&dg[s], 1); atomicAdd(&cn[d], 1); }
        }
    }
}

// ---- scan1: reduce the 8 shards (coalesced strided loads) -> cnt_n, deg_i,
// then block-local exclusive scan of PADDED counts (ceil8). Consumers add bsum[i>>10]. ----
__global__ void scan1_kernel(const int* __restrict__ deg8, const int* __restrict__ cnt8,
                             int* __restrict__ deg_i, int* __restrict__ cnt_n,
                             int* __restrict__ excl, int* __restrict__ bsum, int N) {
    __shared__ int s[SCAN_BS];
    int t = threadIdx.x;
    int i = blockIdx.x * SCAN_BS + t;
    int cntv = 0;
    if (i < N) {
        int degv = 0;
#pragma unroll
        for (int k = 0; k < 8; k++) {
            cntv += cnt8[(size_t)k * NN + i];
            degv += deg8[(size_t)k * NN + i];
        }
        cnt_n[i] = cntv;
        deg_i[i] = degv;
    }
    int v = (i < N) ? ((cntv + 7) & ~7) : 0;
    s[t] = v;
    __syncthreads();
    for (int off = 1; off < SCAN_BS; off <<= 1) {
        int add = (t >= off) ? s[t - off] : 0;
        __syncthreads();
        s[t] += add;
        __syncthreads();
    }
    if (i < N) excl[i] = s[t] - v;   // exclusive within block
    if (t == SCAN_BS - 1) bsum[blockIdx.x] = s[t];
}

__global__ void scan2_kernel(int* __restrict__ bsum, int NB) {
    __shared__ int s[128];
    int t = threadIdx.x;
    int v = (t < NB) ? bsum[t] : 0;
    s[t] = v;
    __syncthreads();
    for (int off = 1; off < 128; off <<= 1) {
        int add = (t >= off) ? s[t - off] : 0;
        __syncthreads();
        s[t] += add;
        __syncthreads();
    }
    if (t < NB) bsum[t] = s[t] - v;  // exclusive
}

// ---- scatter + inline weight: cv[pos] = {src, -dinv[s]*dinv[d]} ----
__global__ void scatter_wgt_kernel(const int* __restrict__ src, const int* __restrict__ dst,
                                   const int* __restrict__ deg_i, const int* __restrict__ rs,
                                   const int* __restrict__ bsum, int* __restrict__ fill,
                                   int2* __restrict__ cv, int E) {
    int e0 = (blockIdx.x * blockDim.x + threadIdx.x) * 2;
#pragma unroll
    for (int q = 0; q < 2; q++) {
        int e = e0 + q;
        if (e < E) {
            int s = src[e], d = dst[e];
            if (s != d) {
                int ds = deg_i[s], dd = deg_i[d];   // ds >= 1 guaranteed (edge e itself)
                float wv = (dd > 0) ? -rsqrtf((float)ds) * rsqrtf((float)dd) : 0.0f;
                int pos = rs[d] + bsum[d >> 10] + atomicAdd(&fill[d], 1);
                cv[pos] = make_int2(s, __float_as_int(wv));
            }
        }
    }
}

// ---- prepB (merged): Bcat = [W2 | W1 | W0-W2] (FI x 3FO) in MFMA B-fragment layout ----
template <int FI, int FO>
__device__ __forceinline__ void prep_one(const float* __restrict__ W,
                                         unsigned short* __restrict__ Bfrag, int id) {
    constexpr int NS = FI / 32;
    int lane = id & 63;
    int s = (id >> 6) % NS;
    int t = (id >> 6) / NS;
    int n = t * 16 + (lane & 15);
    int kbase = s * 32 + (lane >> 4) * 8;
    int sec = n / FO;        // 0 -> W2, 1 -> W1, 2 -> W0 - W2
    int nc  = n % FO;
    ushort8_t out;
#pragma unroll
    for (int j = 0; j < 8; j++) {
        int k = kbase + j;
        float v;
        if (sec == 0)      v = W[(size_t)(2 * FI + k) * FO + nc];
        else if (sec == 1) v = W[(size_t)(1 * FI + k) * FO + nc];
        else               v = W[(size_t)(0 * FI + k) * FO + nc]
                             - W[(size_t)(2 * FI + k) * FO + nc];
        out[j] = f2bf(v);
    }
    *(ushort8_t*)(Bfrag + (size_t)id * 8) = out;
}

__global__ void prepB_all_kernel(const float* __restrict__ W1, const float* __restrict__ W2,
                                 const float* __restrict__ W3,
                                 unsigned short* __restrict__ Bf1,
                                 unsigned short* __restrict__ Bf2,
                                 unsigned short* __restrict__ Bf3) {
    int id = blockIdx.x * blockDim.x + threadIdx.x;
    if (id < 3072)      prep_one<128, 64>(W1, Bf1, id);            // 12*4*64
    else if (id < 3840) prep_one<64, 32>(W2, Bf2, id - 3072);      //  6*2*64
    else if (id < 4032) prep_one<32, 16>(W3, Bf3, id - 3840);      //  3*1*64
}

// ---- MFMA gemm3: Ubf = bf16(x@W2), Tbf = bf16(x@W1), S = x@(W0-W2) fp32 ----
template <int FI, int FO>
__global__ __launch_bounds__(256) void gemmM_kernel(
        const float* __restrict__ x, const unsigned short* __restrict__ Bfrag,
        unsigned short* __restrict__ Tbf, float* __restrict__ S,
        unsigned short* __restrict__ Ubf, int N) {
    constexpr int NT = 3 * FO / 16;   // n-tiles
    constexpr int NS = FI / 32;       // k-steps
    constexpr int NFRAG = NT * NS;
    __shared__ ushort8_t bl[NFRAG * 64];

    const ushort8_t* bsrc = (const ushort8_t*)Bfrag;
    for (int q = threadIdx.x; q < NFRAG * 64; q += 256) bl[q] = bsrc[q];
    __syncthreads();

    const int lane = threadIdx.x & 63;
    const int wave = threadIdx.x >> 6;
    const int m0   = blockIdx.x * 64 + wave * 16;
    const int quad = lane >> 4;
    const int mrow = m0 + (lane & 15);

    floatx4_t acc[NT];
#pragma unroll
    for (int t = 0; t < NT; t++) acc[t] = (floatx4_t){0.f, 0.f, 0.f, 0.f};

#pragma unroll
    for (int s = 0; s < NS; s++) {
        bf16x8_t a;
        if (mrow < N) {
            const float* ap = x + (size_t)mrow * FI + s * 32 + quad * 8;
            float4 a0 = *(const float4*)(ap);
            float4 a1 = *(const float4*)(ap + 4);
            a[0] = (short)f2bf(a0.x); a[1] = (short)f2bf(a0.y);
            a[2] = (short)f2bf(a0.z); a[3] = (short)f2bf(a0.w);
            a[4] = (short)f2bf(a1.x); a[5] = (short)f2bf(a1.y);
            a[6] = (short)f2bf(a1.z); a[7] = (short)f2bf(a1.w);
        } else {
            a = (bf16x8_t){0, 0, 0, 0, 0, 0, 0, 0};
        }
#pragma unroll
        for (int t = 0; t < NT; t++) {
            bf16x8_t b = *(const bf16x8_t*)&bl[(t * NS + s) * 64 + lane];
            acc[t] = __builtin_amdgcn_mfma_f32_16x16x32_bf16(a, b, acc[t], 0, 0, 0);
        }
    }
    // C/D layout: col = lane&15, row = quad*4 + reg   [verified m89/m91]
#pragma unroll
    for (int t = 0; t < NT; t++) {
        int n   = t * 16 + (lane & 15);
        int sec = (t * 16) / FO;          // compile-time per t (FO multiple of 16)
        int nc  = n % FO;
#pragma unroll
        for (int r = 0; r < 4; r++) {
            int m = m0 + quad * 4 + r;
            if (m >= N) continue;
            float v = acc[t][r];
            size_t o = (size_t)m * FO + nc;
            if (sec == 0)      Ubf[o] = f2bf(v);
            else if (sec == 1) Tbf[o] = f2bf(v);
            else               S[o] = v;
        }
    }
}

// ---- propA8: Obf[i] = bf16( T[i] + 2 * sum_p val[p]*Ubf[col[p]] ) ----
template <int FO>
__global__ void propA8_kernel(const unsigned short* __restrict__ Ubf,
                              const unsigned short* __restrict__ Tbf,
                              const int* __restrict__ rs, const int* __restrict__ bsum,
                              const int* __restrict__ cnt_n, const int2* __restrict__ cv,
                              unsigned short* __restrict__ Obf, int N) {
    constexpr int PER = FO / 8;
    unsigned idx = blockIdx.x * blockDim.x + threadIdx.x;
    if (idx >= (unsigned)N * PER) return;
    int i = idx / PER;
    int c = (idx & (PER - 1)) * 8;
    int beg = rs[i] + bsum[i >> 10];
    int end = beg + cnt_n[i];
    float acc[8] = {0.f, 0.f, 0.f, 0.f, 0.f, 0.f, 0.f, 0.f};
    for (int p = beg; p < end; ++p) {
        int2 e = cv[p];
        float wv = __int_as_float(e.y);
        ushort8_t u = *(const ushort8_t*)(Ubf + (size_t)e.x * FO + c);
#pragma unroll
        for (int j = 0; j < 8; j++) acc[j] = fmaf(wv, bf2f(u[j]), acc[j]);
    }
    ushort8_t tv = *(const ushort8_t*)(Tbf + (size_t)i * FO + c);
    ushort8_t o;
#pragma unroll
    for (int j = 0; j < 8; j++) o[j] = f2bf(bf2f(tv[j]) + 2.f * acc[j]);
    *(ushort8_t*)(Obf + (size_t)i * FO + c) = o;
}

// ---- propC8: h[i] = leaky_relu(BN(S[i] + sum_p val[p]*Bbf[col[p]] + b))  (h may == S) ----
template <int FO>
__global__ void propC8_kernel(const unsigned short* __restrict__ Bbf,
                              const float* __restrict__ S,
                              const int* __restrict__ rs, const int* __restrict__ bsum,
                              const int* __restrict__ cnt_n, const int2* __restrict__ cv,
                              const float* __restrict__ b, const float* __restrict__ g,
                              const float* __restrict__ be, const float* __restrict__ m,
                              const float* __restrict__ vv, float* __restrict__ h, int N) {
    constexpr int PER = FO / 8;
    unsigned idx = blockIdx.x * blockDim.x + threadIdx.x;
    if (idx >= (unsigned)N * PER) return;
    int i = idx / PER;
    int c = (idx & (PER - 1)) * 8;
    int beg = rs[i] + bsum[i >> 10];
    int end = beg + cnt_n[i];
    float acc[8] = {0.f, 0.f, 0.f, 0.f, 0.f, 0.f, 0.f, 0.f};
    for (int p = beg; p < end; ++p) {
        int2 e = cv[p];
        float wv = __int_as_float(e.y);
        ushort8_t u = *(const ushort8_t*)(Bbf + (size_t)e.x * FO + c);
#pragma unroll
        for (int j = 0; j < 8; j++) acc[j] = fmaf(wv, bf2f(u[j]), acc[j]);
    }
    const float* sr = S + (size_t)i * FO + c;
    float4 s0 = *(const float4*)(sr);
    float4 s1 = *(const float4*)(sr + 4);
    const float ss[8] = {s0.x, s0.y, s0.z, s0.w, s1.x, s1.y, s1.z, s1.w};
    float out[8];
#pragma unroll
    for (int j = 0; j < 8; j++) {
        int f = c + j;
        float A = g[f] * rsqrtf(vv[f] + BN_EPS);
        float B = be[f] - (m[f] - b[f]) * A;
        float y = (ss[j] + acc[j]) * A + B;
        out[j] = y > 0.0f ? y : 0.01f * y;
    }
    float* hr = h + (size_t)i * FO + c;
    *(float4*)(hr)     = make_float4(out[0], out[1], out[2], out[3]);
    *(float4*)(hr + 4) = make_float4(out[4], out[5], out[6], out[7]);
}

// ---- mean pool v3: thread = (node-lane, feature-quad); float4 loads ----
__global__ __launch_bounds__(256) void pool3_kernel(
        const float* __restrict__ h, const int* __restrict__ batch,
        float* __restrict__ pool, float* __restrict__ cnt, int N) {
    __shared__ float sp[NG * 16];
    __shared__ float sc[NG];
    int t = threadIdx.x;
    for (int i = t; i < NG * 16; i += 256) sp[i] = 0.f;
    for (int i = t; i < NG; i += 256) sc[i] = 0.f;
    __syncthreads();
    const int f4 = (t & 3) * 4;      // feature quad
    const int nl = t >> 2;           // node lane 0..63
    const int base = blockIdx.x * PNPB;
    const int nEnd = min(base + PNPB, N);
    float4 acc = make_float4(0.f, 0.f, 0.f, 0.f);
    float cacc = 0.f;
    int gcur = -1;
    for (int n = base + nl; n < nEnd; n += 64) {
        int g = batch[n];
        if (g != gcur) {
            if (gcur >= 0) {
                atomicAdd(&sp[gcur * 16 + f4 + 0], acc.x);
                atomicAdd(&sp[gcur * 16 + f4 + 1], acc.y);
                atomicAdd(&sp[gcur * 16 + f4 + 2], acc.z);
                atomicAdd(&sp[gcur * 16 + f4 + 3], acc.w);
                if (f4 == 0) atomicAdd(&sc[gcur], cacc);
            }
            gcur = g; acc = make_float4(0.f, 0.f, 0.f, 0.f); cacc = 0.f;
        }
        float4 hv = *(const float4*)(h + (size_t)n * 16 + f4);
        acc.x += hv.x; acc.y += hv.y; acc.z += hv.z; acc.w += hv.w;
        cacc += 1.f;
    }
    if (gcur >= 0) {
        atomicAdd(&sp[gcur * 16 + f4 + 0], acc.x);
        atomicAdd(&sp[gcur * 16 + f4 + 1], acc.y);
        atomicAdd(&sp[gcur * 16 + f4 + 2], acc.z);
        atomicAdd(&sp[gcur * 16 + f4 + 3], acc.w);
        if (f4 == 0) atomicAdd(&sc[gcur], cacc);
    }
    __syncthreads();
    for (int i = t; i < NG * 16; i += 256)
        if (sp[i] != 0.f) unsafeAtomicAdd(&pool[i], sp[i]);
    for (int i = t; i < NG; i += 256)
        if (sc[i] != 0.f) unsafeAtomicAdd(&cnt[i], sc[i]);
}

// ---------------- final linear head ----------------
__global__ void final_kernel(const float* __restrict__ pool, const float* __restrict__ cnt,
                             const float* __restrict__ lw, const float* __restrict__ lb,
                             float* __restrict__ out) {
    int idx = threadIdx.x;
    if (idx >= NG * 2) return;
    int g = idx >> 1;
    int c = idx & 1;
    float inv = 1.0f / fmaxf(cnt[g], 1.0f);
    float acc = 0.0f;
#pragma unroll
    for (int f = 0; f < 16; f++) acc += pool[g * 16 + f] * lw[c * 16 + f];
    out[idx] = acc * inv + lb[c];
}

extern "C" void kernel_launch(void* const* d_in, const int* in_sizes, int n_in,
                              void* d_out, int out_size, void* d_ws, size_t ws_size,
                              hipStream_t stream) {
    const float* x    = (const float*)d_in[0];
    const int*   ei   = (const int*)d_in[1];
    const int*   batch= (const int*)d_in[2];
    const float* W1 = (const float*)d_in[3];
    const float* b1 = (const float*)d_in[4];
    const float* g1 = (const float*)d_in[5];
    const float* be1= (const float*)d_in[6];
    const float* m1 = (const float*)d_in[7];
    const float* v1 = (const float*)d_in[8];
    const float* W2 = (const float*)d_in[9];
    const float* b2 = (const float*)d_in[10];
    const float* g2 = (const float*)d_in[11];
    const float* be2= (const float*)d_in[12];
    const float* m2 = (const float*)d_in[13];
    const float* v2 = (const float*)d_in[14];
    const float* W3 = (const float*)d_in[15];
    const float* b3 = (const float*)d_in[16];
    const float* g3 = (const float*)d_in[17];
    const float* be3= (const float*)d_in[18];
    const float* m3 = (const float*)d_in[19];
    const float* v3 = (const float*)d_in[20];
    const float* lw = (const float*)d_in[21];
    const float* lb = (const float*)d_in[22];

    const int* src = ei;            // edge_index[0]
    const int* dst = ei + NE;       // edge_index[1]

    float* ws = (float*)d_ws;
    // ---- workspace layout (4-byte units, 16B-aligned; ~102 MB total) ----
    size_t off = 0;
    int*   deg8  = (int*)(ws + off); off += 8 * (size_t)NN;   // XCD-sharded out-degree
    int*   cnt8  = (int*)(ws + off); off += 8 * (size_t)NN;   // XCD-sharded in-degree
    int*   fill  = (int*)(ws + off); off += NN;
    float* pool  = ws + off; off += NG * 16;
    float* cnt   = ws + off; off += NG;
    size_t zero_bytes = off * sizeof(float);       // one memset covers all of the above
    int*   deg_i = (int*)(ws + off); off += NN;    // reduced (written by scan1)
    int*   cnt_n = (int*)(ws + off); off += NN;    // reduced (written by scan1)
    int*   rs    = (int*)(ws + off); off += NN + 4;  // padded per-1024-block excl scan
    int*   bsum  = (int*)(ws + off); off += 128;
    int2*  cv    = (int2*)(ws + off); off += 2 * (size_t)MAXSLOT;  // interleaved {col,val}
    unsigned short* Tbf = (unsigned short*)(ws + off); off += (size_t)NN * 32;  // NN*64 bf16
    float* Bb   = ws + off; off += (size_t)NN * 64;          // S1 / h1 (fp32)
    float* D    = ws + off; off += (size_t)NN * 32;          // S2 / h2
    float* C16  = ws + off; off += (size_t)NN * 16;          // S3 / h3
    unsigned short* Ubf  = (unsigned short*)(ws + off); off += (size_t)NN * 32;  // NN*64 bf16
    unsigned short* Bbbf = (unsigned short*)(ws + off); off += (size_t)NN * 32;  // NN*64 bf16
    unsigned short* Bf1  = (unsigned short*)(ws + off); off += 12288;  // 24576 bf16
    unsigned short* Bf2  = (unsigned short*)(ws + off); off += 3072;   //  6144 bf16
    unsigned short* Bf3  = (unsigned short*)(ws + off); off += 768;    //  1536 bf16

    hipMemsetAsync(ws, 0, zero_bytes, stream);

    // ---- CSR build: hist8 -> scan1(reduce+scan) -> scan2 -> scatter+weight ----
    hist_kernel<<<cdiv(NE, 2 * BS), BS, 0, stream>>>(src, dst, deg8, cnt8, NE);
    prepB_all_kernel<<<16, BS, 0, stream>>>(W1, W2, W3, Bf1, Bf2, Bf3);
    scan1_kernel<<<NB_SCAN, SCAN_BS, 0, stream>>>(deg8, cnt8, deg_i, cnt_n, rs, bsum, NN);
    scan2_kernel<<<1, 128, 0, stream>>>(bsum, NB_SCAN);
    scatter_wgt_kernel<<<cdiv(NE, 2 * BS), BS, 0, stream>>>(src, dst, deg_i, rs, bsum,
                                                            fill, cv, NE);

    // ---- layer 1: 128 -> 64 ----
    gemmM_kernel<128, 64><<<cdiv(NN, 64), 256, 0, stream>>>(x, Bf1, Tbf, Bb, Ubf, NN);
    propA8_kernel<64><<<cdiv((long long)NN * 8, BS), BS, 0, stream>>>(Ubf, Tbf, rs, bsum,
                                                                      cnt_n, cv, Bbbf, NN);
    propC8_kernel<64><<<cdiv((long long)NN * 8, BS), BS, 0, stream>>>(Bbbf, Bb, rs, bsum,
                                                                      cnt_n, cv,
                                                                      b1, g1, be1, m1, v1, Bb, NN);
    // ---- layer 2: 64 -> 32 ----
    gemmM_kernel<64, 32><<<cdiv(NN, 64), 256, 0, stream>>>(Bb, Bf2, Tbf, D, Ubf, NN);
    propA8_kernel<32><<<cdiv((long long)NN * 4, BS), BS, 0, stream>>>(Ubf, Tbf, rs, bsum,
                                                                      cnt_n, cv, Bbbf, NN);
    propC8_kernel<32><<<cdiv((long long)NN * 4, BS), BS, 0, stream>>>(Bbbf, D, rs, bsum,
                                                                      cnt_n, cv,
                                                                      b2, g2, be2, m2, v2, D, NN);
    // ---- layer 3: 32 -> 16 ----
    gemmM_kernel<32, 16><<<cdiv(NN, 64), 256, 0, stream>>>(D, Bf3, Tbf, C16, Ubf, NN);
    propA8_kernel<16><<<cdiv((long long)NN * 2, BS), BS, 0, stream>>>(Ubf, Tbf, rs, bsum,
                                                                      cnt_n, cv, Bbbf, NN);
    propC8_kernel<16><<<cdiv((long long)NN * 2, BS), BS, 0, stream>>>(Bbbf, C16, rs, bsum,
                                                                      cnt_n, cv,
                                                                      b3, g3, be3, m3, v3, C16, NN);
    // ---- pool + head ----
    pool3_kernel<<<cdiv(NN, PNPB), 256, 0, stream>>>(C16, batch, pool, cnt, NN);
    final_kernel<<<1, 128, 0, stream>>>(pool, cnt, lw, lb, (float*)d_out);
}

// Round 12
// 373.603 us; speedup vs baseline: 1.3097x; 1.0989x over previous
//
#include <hip/hip_runtime.h>
#include <hip/hip_bf16.h>

// Problem constants (match reference)
#define NN 100000   // nodes
#define NE 640000   // edges
#define NG 64       // graphs
#define BN_EPS 1e-5f

#define BS 256      // block size
#define PNPB 256    // nodes per block in pool
#define CAP 32      // fixed CSR slots per row (P(indeg>=32) ~ 3e-13/node; guarded anyway)

typedef __attribute__((ext_vector_type(8))) unsigned short ushort8_t;
typedef __attribute__((ext_vector_type(4))) unsigned short ushort4_t;
typedef __attribute__((ext_vector_type(8))) short bf16x8_t;    // MFMA A/B frag (4 VGPR)
typedef __attribute__((ext_vector_type(4))) float floatx4_t;   // MFMA C/D frag

static inline int cdiv(long long a, int b) { return (int)((a + b - 1) / b); }

__device__ __forceinline__ float bf2f(unsigned short u) {
    union { unsigned int i; float f; } c; c.i = ((unsigned int)u) << 16; return c.f;
}
__device__ __forceinline__ unsigned short f2bf(float f) {   // RNE
    unsigned int u = __float_as_uint(f);
    u += 0x7fffu + ((u >> 16) & 1u);
    return (unsigned short)(u >> 16);
}

// ---- scatter: fixed-stride CSR build in ONE edge pass (R11 PMC: atomics execute
// memory-side at ~25 G/s regardless of sharding -> minimize atomic count & passes).
// fill[d] slot counter IS the in-degree; deg_o[s] accumulates out-degree for weights. ----
__global__ void scatter_kernel(const int* __restrict__ src, const int* __restrict__ dst,
                               int* __restrict__ fill, int* __restrict__ deg_o,
                               int2* __restrict__ cv, int E) {
    int e0 = (blockIdx.x * blockDim.x + threadIdx.x) * 2;
#pragma unroll
    for (int q = 0; q < 2; q++) {
        int e = e0 + q;
        if (e < E) {
            int s = src[e], d = dst[e];
            if (s != d) {
                atomicAdd(&deg_o[s], 1);
                int pos = atomicAdd(&fill[d], 1) & (CAP - 1);   // guard: wrap, never OOB
                cv[(size_t)d * CAP + pos] = make_int2(s, 0);
            }
        }
    }
}

// ---- wfix: val[slot] = -rsqrt(deg_o[src]) * rsqrt(deg_o[dst]) (degrees now complete) ----
__global__ void wfix_kernel(const int* __restrict__ deg_o, const int* __restrict__ fill,
                            int2* __restrict__ cv, int N) {
    int idx = blockIdx.x * blockDim.x + threadIdx.x;   // one thread per slot
    int i = idx >> 5;
    if (i >= N) return;
    int j = idx & (CAP - 1);
    int cnt = min(fill[i], CAP);
    if (j >= cnt) return;
    int s = cv[idx].x;
    int ds = deg_o[s];          // >= 1 (this edge has src=s)
    int dd = deg_o[i];          // out-degree of dst, may be 0
    float wv = (dd > 0) ? -rsqrtf((float)ds) * rsqrtf((float)dd) : 0.0f;
    cv[idx].y = __float_as_int(wv);
}

// ---- prepB (merged): Bcat = [W2 | W1 | W0-W2] (FI x 3FO) in MFMA B-fragment layout ----
template <int FI, int FO>
__device__ __forceinline__ void prep_one(const float* __restrict__ W,
                                         unsigned short* __restrict__ Bfrag, int id) {
    constexpr int NS = FI / 32;
    int lane = id & 63;
    int s = (id >> 6) % NS;
    int t = (id >> 6) / NS;
    int n = t * 16 + (lane & 15);
    int kbase = s * 32 + (lane >> 4) * 8;
    int sec = n / FO;        // 0 -> W2, 1 -> W1, 2 -> W0 - W2
    int nc  = n % FO;
    ushort8_t out;
#pragma unroll
    for (int j = 0; j < 8; j++) {
        int k = kbase + j;
        float v;
        if (sec == 0)      v = W[(size_t)(2 * FI + k) * FO + nc];
        else if (sec == 1) v = W[(size_t)(1 * FI + k) * FO + nc];
        else               v = W[(size_t)(0 * FI + k) * FO + nc]
                             - W[(size_t)(2 * FI + k) * FO + nc];
        out[j] = f2bf(v);
    }
    *(ushort8_t*)(Bfrag + (size_t)id * 8) = out;
}

__global__ void prepB_all_kernel(const float* __restrict__ W1, const float* __restrict__ W2,
                                 const float* __restrict__ W3,
                                 unsigned short* __restrict__ Bf1,
                                 unsigned short* __restrict__ Bf2,
                                 unsigned short* __restrict__ Bf3) {
    int id = blockIdx.x * blockDim.x + threadIdx.x;
    if (id < 3072)      prep_one<128, 64>(W1, Bf1, id);            // 12*4*64
    else if (id < 3840) prep_one<64, 32>(W2, Bf2, id - 3072);      //  6*2*64
    else if (id < 4032) prep_one<32, 16>(W3, Bf3, id - 3840);      //  3*1*64
}

// ---- MFMA gemm3: Ubf = bf16(x@W2), Tbf = bf16(x@W1), Sbf = bf16(x@(W0-W2)) ----
// Input TI = float (layer 1, external x) or unsigned short (bf16 h from prior layer;
// identical numerics: the fp32 path rounds to bf16 at the same point anyway).
template <int FI, int FO, typename TI>
__global__ __launch_bounds__(256) void gemmM_kernel(
        const TI* __restrict__ x, const unsigned short* __restrict__ Bfrag,
        unsigned short* __restrict__ Tbf, unsigned short* __restrict__ Sbf,
        unsigned short* __restrict__ Ubf, int N) {
    constexpr int NT = 3 * FO / 16;   // n-tiles
    constexpr int NS = FI / 32;       // k-steps
    constexpr int NFRAG = NT * NS;
    __shared__ ushort8_t bl[NFRAG * 64];

    const ushort8_t* bsrc = (const ushort8_t*)Bfrag;
    for (int q = threadIdx.x; q < NFRAG * 64; q += 256) bl[q] = bsrc[q];
    __syncthreads();

    const int lane = threadIdx.x & 63;
    const int wave = threadIdx.x >> 6;
    const int m0   = blockIdx.x * 64 + wave * 16;
    const int quad = lane >> 4;
    const int mrow = m0 + (lane & 15);

    floatx4_t acc[NT];
#pragma unroll
    for (int t = 0; t < NT; t++) acc[t] = (floatx4_t){0.f, 0.f, 0.f, 0.f};

#pragma unroll
    for (int s = 0; s < NS; s++) {
        bf16x8_t a;
        if (mrow < N) {
            if constexpr (sizeof(TI) == 4) {
                const float* ap = (const float*)x + (size_t)mrow * FI + s * 32 + quad * 8;
                float4 a0 = *(const float4*)(ap);
                float4 a1 = *(const float4*)(ap + 4);
                a[0] = (short)f2bf(a0.x); a[1] = (short)f2bf(a0.y);
                a[2] = (short)f2bf(a0.z); a[3] = (short)f2bf(a0.w);
                a[4] = (short)f2bf(a1.x); a[5] = (short)f2bf(a1.y);
                a[6] = (short)f2bf(a1.z); a[7] = (short)f2bf(a1.w);
            } else {
                const unsigned short* ap = (const unsigned short*)x
                                         + (size_t)mrow * FI + s * 32 + quad * 8;
                a = *(const bf16x8_t*)ap;   // already bf16 bits
            }
        } else {
            a = (bf16x8_t){0, 0, 0, 0, 0, 0, 0, 0};
        }
#pragma unroll
        for (int t = 0; t < NT; t++) {
            bf16x8_t b = *(const bf16x8_t*)&bl[(t * NS + s) * 64 + lane];
            acc[t] = __builtin_amdgcn_mfma_f32_16x16x32_bf16(a, b, acc[t], 0, 0, 0);
        }
    }
    // C/D layout: col = lane&15, row = quad*4 + reg   [verified m89/m91]
#pragma unroll
    for (int t = 0; t < NT; t++) {
        int n   = t * 16 + (lane & 15);
        int sec = (t * 16) / FO;          // compile-time per t (FO multiple of 16)
        int nc  = n % FO;
#pragma unroll
        for (int r = 0; r < 4; r++) {
            int m = m0 + quad * 4 + r;
            if (m >= N) continue;
            unsigned short v = f2bf(acc[t][r]);
            size_t o = (size_t)m * FO + nc;
            if (sec == 0)      Ubf[o] = v;
            else if (sec == 1) Tbf[o] = v;
            else               Sbf[o] = v;
        }
    }
}

// ---- propA8: Obf[i] = bf16( T[i] + 2 * sum_p val[p]*Ubf[col[p]] ) ----
// Thread per (row, 8-feature chunk); fixed-stride CSR: beg = i*CAP, cnt = fill[i].
template <int FO>
__global__ void propA8_kernel(const unsigned short* __restrict__ Ubf,
                              const unsigned short* __restrict__ Tbf,
                              const int* __restrict__ fill, const int2* __restrict__ cv,
                              unsigned short* __restrict__ Obf, int N) {
    constexpr int PER = FO / 8;
    unsigned idx = blockIdx.x * blockDim.x + threadIdx.x;
    if (idx >= (unsigned)N * PER) return;
    int i = idx / PER;
    int c = (idx & (PER - 1)) * 8;
    int beg = i * CAP;
    int end = beg + min(fill[i], CAP);
    float acc[8] = {0.f, 0.f, 0.f, 0.f, 0.f, 0.f, 0.f, 0.f};
    for (int p = beg; p < end; ++p) {
        int2 e = cv[p];
        float wv = __int_as_float(e.y);
        ushort8_t u = *(const ushort8_t*)(Ubf + (size_t)e.x * FO + c);
#pragma unroll
        for (int j = 0; j < 8; j++) acc[j] = fmaf(wv, bf2f(u[j]), acc[j]);
    }
    ushort8_t tv = *(const ushort8_t*)(Tbf + (size_t)i * FO + c);
    ushort8_t o;
#pragma unroll
    for (int j = 0; j < 8; j++) o[j] = f2bf(bf2f(tv[j]) + 2.f * acc[j]);
    *(ushort8_t*)(Obf + (size_t)i * FO + c) = o;
}

// ---- propC8: h[i] = leaky_relu(BN(S[i] + sum_p val[p]*Bbf[col[p]] + b)), bf16 S/h (h==S ok) ----
template <int FO>
__global__ void propC8_kernel(const unsigned short* __restrict__ Bbf,
                              const unsigned short* __restrict__ Sbf,
                              const int* __restrict__ fill, const int2* __restrict__ cv,
                              const float* __restrict__ b, const float* __restrict__ g,
                              const float* __restrict__ be, const float* __restrict__ m,
                              const float* __restrict__ vv,
                              unsigned short* __restrict__ h, int N) {
    constexpr int PER = FO / 8;
    unsigned idx = blockIdx.x * blockDim.x + threadIdx.x;
    if (idx >= (unsigned)N * PER) return;
    int i = idx / PER;
    int c = (idx & (PER - 1)) * 8;
    int beg = i * CAP;
    int end = beg + min(fill[i], CAP);
    float acc[8] = {0.f, 0.f, 0.f, 0.f, 0.f, 0.f, 0.f, 0.f};
    for (int p = beg; p < end; ++p) {
        int2 e = cv[p];
        float wv = __int_as_float(e.y);
        ushort8_t u = *(const ushort8_t*)(Bbf + (size_t)e.x * FO + c);
#pragma unroll
        for (int j = 0; j < 8; j++) acc[j] = fmaf(wv, bf2f(u[j]), acc[j]);
    }
    ushort8_t sv = *(const ushort8_t*)(Sbf + (size_t)i * FO + c);
    ushort8_t o;
#pragma unroll
    for (int j = 0; j < 8; j++) {
        int f = c + j;
        float A = g[f] * rsqrtf(vv[f] + BN_EPS);
        float B = be[f] - (m[f] - b[f]) * A;
        float y = (bf2f(sv[j]) + acc[j]) * A + B;
        y = y > 0.0f ? y : 0.01f * y;
        o[j] = f2bf(y);
    }
    *(ushort8_t*)(h + (size_t)i * FO + c) = o;
}

// ---- mean pool: thread = (node-lane, feature-quad); bf16 h, 8B loads ----
__global__ __launch_bounds__(256) void pool3_kernel(
        const unsigned short* __restrict__ h, const int* __restrict__ batch,
        float* __restrict__ pool, float* __restrict__ cnt, int N) {
    __shared__ float sp[NG * 16];
    __shared__ float sc[NG];
    int t = threadIdx.x;
    for (int i = t; i < NG * 16; i += 256) sp[i] = 0.f;
    for (int i = t; i < NG; i += 256) sc[i] = 0.f;
    __syncthreads();
    const int f4 = (t & 3) * 4;      // feature quad
    const int nl = t >> 2;           // node lane 0..63
    const int base = blockIdx.x * PNPB;
    const int nEnd = min(base + PNPB, N);
    float4 acc = make_float4(0.f, 0.f, 0.f, 0.f);
    float cacc = 0.f;
    int gcur = -1;
    for (int n = base + nl; n < nEnd; n += 64) {
        int g = batch[n];
        if (g != gcur) {
            if (gcur >= 0) {
                atomicAdd(&sp[gcur * 16 + f4 + 0], acc.x);
                atomicAdd(&sp[gcur * 16 + f4 + 1], acc.y);
                atomicAdd(&sp[gcur * 16 + f4 + 2], acc.z);
                atomicAdd(&sp[gcur * 16 + f4 + 3], acc.w);
                if (f4 == 0) atomicAdd(&sc[gcur], cacc);
            }
            gcur = g; acc = make_float4(0.f, 0.f, 0.f, 0.f); cacc = 0.f;
        }
        ushort4_t hv = *(const ushort4_t*)(h + (size_t)n * 16 + f4);
        acc.x += bf2f(hv.x); acc.y += bf2f(hv.y);
        acc.z += bf2f(hv.z); acc.w += bf2f(hv.w);
        cacc += 1.f;
    }
    if (gcur >= 0) {
        atomicAdd(&sp[gcur * 16 + f4 + 0], acc.x);
        atomicAdd(&sp[gcur * 16 + f4 + 1], acc.y);
        atomicAdd(&sp[gcur * 16 + f4 + 2], acc.z);
        atomicAdd(&sp[gcur * 16 + f4 + 3], acc.w);
        if (f4 == 0) atomicAdd(&sc[gcur], cacc);
    }
    __syncthreads();
    for (int i = t; i < NG * 16; i += 256)
        if (sp[i] != 0.f) unsafeAtomicAdd(&pool[i], sp[i]);
    for (int i = t; i < NG; i += 256)
        if (sc[i] != 0.f) unsafeAtomicAdd(&cnt[i], sc[i]);
}

// ---------------- final linear head ----------------
__global__ void final_kernel(const float* __restrict__ pool, const float* __restrict__ cnt,
                             const float* __restrict__ lw, const float* __restrict__ lb,
                             float* __restrict__ out) {
    int idx = threadIdx.x;
    if (idx >= NG * 2) return;
    int g = idx >> 1;
    int c = idx & 1;
    float inv = 1.0f / fmaxf(cnt[g], 1.0f);
    float acc = 0.0f;
#pragma unroll
    for (int f = 0; f < 16; f++) acc += pool[g * 16 + f] * lw[c * 16 + f];
    out[idx] = acc * inv + lb[c];
}

extern "C" void kernel_launch(void* const* d_in, const int* in_sizes, int n_in,
                              void* d_out, int out_size, void* d_ws, size_t ws_size,
                              hipStream_t stream) {
    const float* x    = (const float*)d_in[0];
    const int*   ei   = (const int*)d_in[1];
    const int*   batch= (const int*)d_in[2];
    const float* W1 = (const float*)d_in[3];
    const float* b1 = (const float*)d_in[4];
    const float* g1 = (const float*)d_in[5];
    const float* be1= (const float*)d_in[6];
    const float* m1 = (const float*)d_in[7];
    const float* v1 = (const float*)d_in[8];
    const float* W2 = (const float*)d_in[9];
    const float* b2 = (const float*)d_in[10];
    const float* g2 = (const float*)d_in[11];
    const float* be2= (const float*)d_in[12];
    const float* m2 = (const float*)d_in[13];
    const float* v2 = (const float*)d_in[14];
    const float* W3 = (const float*)d_in[15];
    const float* b3 = (const float*)d_in[16];
    const float* g3 = (const float*)d_in[17];
    const float* be3= (const float*)d_in[18];
    const float* m3 = (const float*)d_in[19];
    const float* v3 = (const float*)d_in[20];
    const float* lw = (const float*)d_in[21];
    const float* lb = (const float*)d_in[22];

    const int* src = ei;            // edge_index[0]
    const int* dst = ei + NE;       // edge_index[1]

    float* ws = (float*)d_ws;
    // ---- workspace layout (4-byte units, 16B-aligned; ~88 MB total) ----
    size_t off = 0;
    int*   fill  = (int*)(ws + off); off += NN;    // in-degree / slot counters
    int*   deg_o = (int*)(ws + off); off += NN;    // out-degree (weights)
    float* pool  = ws + off; off += NG * 16;
    float* cnt   = ws + off; off += NG;
    size_t zero_bytes = off * sizeof(float);       // one memset covers all of the above
    int2*  cv    = (int2*)(ws + off); off += 2 * (size_t)NN * CAP;  // fixed-stride {col,val}
    unsigned short* Tbf  = (unsigned short*)(ws + off); off += (size_t)NN * 32;  // NN*64 bf16
    unsigned short* Ubf  = (unsigned short*)(ws + off); off += (size_t)NN * 32;
    unsigned short* Bbbf = (unsigned short*)(ws + off); off += (size_t)NN * 32;
    unsigned short* S1bf = (unsigned short*)(ws + off); off += (size_t)NN * 32;  // S1 / h1
    unsigned short* S2bf = (unsigned short*)(ws + off); off += (size_t)NN * 16;  // S2 / h2
    unsigned short* S3bf = (unsigned short*)(ws + off); off += (size_t)NN * 8;   // S3 / h3
    unsigned short* Bf1  = (unsigned short*)(ws + off); off += 12288;  // 24576 bf16
    unsigned short* Bf2  = (unsigned short*)(ws + off); off += 3072;   //  6144 bf16
    unsigned short* Bf3  = (unsigned short*)(ws + off); off += 768;    //  1536 bf16

    hipMemsetAsync(ws, 0, zero_bytes, stream);

    // ---- CSR build: one edge pass (scatter) + slot-stream weight pass ----
    scatter_kernel<<<cdiv(NE, 2 * BS), BS, 0, stream>>>(src, dst, fill, deg_o, cv, NE);
    prepB_all_kernel<<<16, BS, 0, stream>>>(W1, W2, W3, Bf1, Bf2, Bf3);
    wfix_kernel<<<cdiv((long long)NN * CAP, BS), BS, 0, stream>>>(deg_o, fill, cv, NN);

    // ---- layer 1: 128 -> 64 ----
    gemmM_kernel<128, 64, float><<<cdiv(NN, 64), 256, 0, stream>>>(x, Bf1, Tbf, S1bf, Ubf, NN);
    propA8_kernel<64><<<cdiv((long long)NN * 8, BS), BS, 0, stream>>>(Ubf, Tbf, fill, cv, Bbbf, NN);
    propC8_kernel<64><<<cdiv((long long)NN * 8, BS), BS, 0, stream>>>(Bbbf, S1bf, fill, cv,
                                                                      b1, g1, be1, m1, v1, S1bf, NN);
    // ---- layer 2: 64 -> 32 ----
    gemmM_kernel<64, 32, unsigned short><<<cdiv(NN, 64), 256, 0, stream>>>(S1bf, Bf2, Tbf, S2bf, Ubf, NN);
    propA8_kernel<32><<<cdiv((long long)NN * 4, BS), BS, 0, stream>>>(Ubf, Tbf, fill, cv, Bbbf, NN);
    propC8_kernel<32><<<cdiv((long long)NN * 4, BS), BS, 0, stream>>>(Bbbf, S2bf, fill, cv,
                                                                      b2, g2, be2, m2, v2, S2bf, NN);
    // ---- layer 3: 32 -> 16 ----
    gemmM_kernel<32, 16, unsigned short><<<cdiv(NN, 64), 256, 0, stream>>>(S2bf, Bf3, Tbf, S3bf, Ubf, NN);
    propA8_kernel<16><<<cdiv((long long)NN * 2, BS), BS, 0, stream>>>(Ubf, Tbf, fill, cv, Bbbf, NN);
    propC8_kernel<16><<<cdiv((long long)NN * 2, BS), BS, 0, stream>>>(Bbbf, S3bf, fill, cv,
                                                                      b3, g3, be3, m3, v3, S3bf, NN);
    // ---- pool + head ----
    pool3_kernel<<<cdiv(NN, PNPB), 256, 0, stream>>>(S3bf, batch, pool, cnt, NN);
    final_kernel<<<1, 128, 0, stream>>>(pool, cnt, lw, lb, (float*)d_out);
}

// Round 14
// 360.666 us; speedup vs baseline: 1.3566x; 1.0359x over previous
//
#include <hip/hip_runtime.h>
#include <hip/hip_bf16.h>

// Problem constants (match reference)
#define NN 100000   // nodes
#define NE 640000   // edges
#define NG 64       // graphs
#define BN_EPS 1e-5f

#define BS 256      // block size
#define PNPB 256    // nodes per block in pool
#define CAP 32      // fixed CSR slots per row (P(indeg>=32) ~ 3e-13/node; guarded anyway)

// fused1 grid partition: [scatter | gemm layer-1]  (prepB must stay a SEPARATE
// prior launch: R13 fused it in and gemm blocks raced the Bf1 writes -> absmax 3.4)
#define NB_SCAT 1250                 // cdiv(NE, 512)
#define NB_G1   1563                 // cdiv(NN, 64)

typedef __attribute__((ext_vector_type(8))) unsigned short ushort8_t;
typedef __attribute__((ext_vector_type(4))) unsigned short ushort4_t;
typedef __attribute__((ext_vector_type(8))) short bf16x8_t;    // MFMA A/B frag (4 VGPR)
typedef __attribute__((ext_vector_type(4))) float floatx4_t;   // MFMA C/D frag

static inline int cdiv(long long a, int b) { return (int)((a + b - 1) / b); }

__device__ __forceinline__ float bf2f(unsigned short u) {
    union { unsigned int i; float f; } c; c.i = ((unsigned int)u) << 16; return c.f;
}
__device__ __forceinline__ unsigned short f2bf(float f) {   // RNE
    unsigned int u = __float_as_uint(f);
    u += 0x7fffu + ((u >> 16) & 1u);
    return (unsigned short)(u >> 16);
}

// ---- prepB piece: Bcat = [W2 | W1 | W0-W2] (FI x 3FO) in MFMA B-fragment layout ----
template <int FI, int FO>
__device__ __forceinline__ void prep_one(const float* __restrict__ W,
                                         unsigned short* __restrict__ Bfrag, int id) {
    constexpr int NS = FI / 32;
    int lane = id & 63;
    int s = (id >> 6) % NS;
    int t = (id >> 6) / NS;
    int n = t * 16 + (lane & 15);
    int kbase = s * 32 + (lane >> 4) * 8;
    int sec = n / FO;        // 0 -> W2, 1 -> W1, 2 -> W0 - W2
    int nc  = n % FO;
    ushort8_t out;
#pragma unroll
    for (int j = 0; j < 8; j++) {
        int k = kbase + j;
        float v;
        if (sec == 0)      v = W[(size_t)(2 * FI + k) * FO + nc];
        else if (sec == 1) v = W[(size_t)(1 * FI + k) * FO + nc];
        else               v = W[(size_t)(0 * FI + k) * FO + nc]
                             - W[(size_t)(2 * FI + k) * FO + nc];
        out[j] = f2bf(v);
    }
    *(ushort8_t*)(Bfrag + (size_t)id * 8) = out;
}

// Separate launch, stream-ordered BEFORE any consumer of Bf1/2/3.
__global__ void prepB_all_kernel(const float* __restrict__ W1, const float* __restrict__ W2,
                                 const float* __restrict__ W3,
                                 unsigned short* __restrict__ Bf1,
                                 unsigned short* __restrict__ Bf2,
                                 unsigned short* __restrict__ Bf3) {
    int id = blockIdx.x * blockDim.x + threadIdx.x;
    if (id < 3072)      prep_one<128, 64>(W1, Bf1, id);            // 12*4*64
    else if (id < 3840) prep_one<64, 32>(W2, Bf2, id - 3072);      //  6*2*64
    else if (id < 4032) prep_one<32, 16>(W3, Bf3, id - 3840);      //  3*1*64
}

// ---- gemm body: Ubf = bf16(x@W2), Tbf = bf16(x@W1), Sbf = bf16(x@(W0-W2)) ----
// Whole block enters together (uniform branch) -> __syncthreads is safe.
template <int FI, int FO, typename TI>
__device__ __forceinline__ void gemm_body(
        const TI* __restrict__ x, const unsigned short* __restrict__ Bfrag,
        unsigned short* __restrict__ Tbf, unsigned short* __restrict__ Sbf,
        unsigned short* __restrict__ Ubf, int N, ushort8_t* bl, int gblk) {
    constexpr int NT = 3 * FO / 16;   // n-tiles
    constexpr int NS = FI / 32;       // k-steps
    constexpr int NFRAG = NT * NS;

    const ushort8_t* bsrc = (const ushort8_t*)Bfrag;
    for (int q = threadIdx.x; q < NFRAG * 64; q += 256) bl[q] = bsrc[q];
    __syncthreads();

    const int lane = threadIdx.x & 63;
    const int wave = threadIdx.x >> 6;
    const int m0   = gblk * 64 + wave * 16;
    const int quad = lane >> 4;
    const int mrow = m0 + (lane & 15);

    floatx4_t acc[NT];
#pragma unroll
    for (int t = 0; t < NT; t++) acc[t] = (floatx4_t){0.f, 0.f, 0.f, 0.f};

#pragma unroll
    for (int s = 0; s < NS; s++) {
        bf16x8_t a;
        if (mrow < N) {
            if constexpr (sizeof(TI) == 4) {
                const float* ap = (const float*)x + (size_t)mrow * FI + s * 32 + quad * 8;
                float4 a0 = *(const float4*)(ap);
                float4 a1 = *(const float4*)(ap + 4);
                a[0] = (short)f2bf(a0.x); a[1] = (short)f2bf(a0.y);
                a[2] = (short)f2bf(a0.z); a[3] = (short)f2bf(a0.w);
                a[4] = (short)f2bf(a1.x); a[5] = (short)f2bf(a1.y);
                a[6] = (short)f2bf(a1.z); a[7] = (short)f2bf(a1.w);
            } else {
                const unsigned short* ap = (const unsigned short*)x
                                         + (size_t)mrow * FI + s * 32 + quad * 8;
                a = *(const bf16x8_t*)ap;   // already bf16 bits
            }
        } else {
            a = (bf16x8_t){0, 0, 0, 0, 0, 0, 0, 0};
        }
#pragma unroll
        for (int t = 0; t < NT; t++) {
            bf16x8_t b = *(const bf16x8_t*)&bl[(t * NS + s) * 64 + lane];
            acc[t] = __builtin_amdgcn_mfma_f32_16x16x32_bf16(a, b, acc[t], 0, 0, 0);
        }
    }
    // C/D layout: col = lane&15, row = quad*4 + reg   [verified m89/m91]
#pragma unroll
    for (int t = 0; t < NT; t++) {
        int n   = t * 16 + (lane & 15);
        int sec = (t * 16) / FO;          // compile-time per t (FO multiple of 16)
        int nc  = n % FO;
#pragma unroll
        for (int r = 0; r < 4; r++) {
            int m = m0 + quad * 4 + r;
            if (m >= N) continue;
            unsigned short v = f2bf(acc[t][r]);
            size_t o = (size_t)m * FO + nc;
            if (sec == 0)      Ubf[o] = v;
            else if (sec == 1) Tbf[o] = v;
            else               Sbf[o] = v;
        }
    }
}

// ---- fused1: heterogeneous grid = [scatter | gemm layer-1] ----
// Scatter blocks are atomic-latency-bound with idle VALU/MFMA (R12 PMC: 0.4%
// VALUBusy); gemm blocks co-schedule on the same CUs (m114 overlap). The two
// paths touch disjoint buffers; Bf1 is produced by the PRIOR prepB launch.
__global__ __launch_bounds__(256) void fused1_kernel(
        const int* __restrict__ src, const int* __restrict__ dst,
        int* __restrict__ fill, int* __restrict__ deg_o, int* __restrict__ col,
        const unsigned short* __restrict__ Bf1,
        const float* __restrict__ x, unsigned short* __restrict__ Tbf,
        unsigned short* __restrict__ Sbf, unsigned short* __restrict__ Ubf,
        int E, int N) {
    __shared__ ushort8_t bl[12 * 4 * 64];   // layer-1 B fragments (48 KB)
    int bid = blockIdx.x;
    if (bid < NB_SCAT) {
        int e0 = (bid * 256 + threadIdx.x) * 2;
#pragma unroll
        for (int q = 0; q < 2; q++) {
            int e = e0 + q;
            if (e < E) {
                int s = src[e], d = dst[e];
                if (s != d) {
                    atomicAdd(&deg_o[s], 1);
                    int pos = atomicAdd(&fill[d], 1) & (CAP - 1);   // wrap guard
                    col[(size_t)d * CAP + pos] = s;
                }
            }
        }
    } else {
        gemm_body<128, 64, float>(x, Bf1, Tbf, Sbf, Ubf, N, bl, bid - NB_SCAT);
    }
}

// ---- standalone gemm for layers 2/3 (bf16 input) ----
template <int FI, int FO>
__global__ __launch_bounds__(256) void gemmM_kernel(
        const unsigned short* __restrict__ x, const unsigned short* __restrict__ Bfrag,
        unsigned short* __restrict__ Tbf, unsigned short* __restrict__ Sbf,
        unsigned short* __restrict__ Ubf, int N) {
    __shared__ ushort8_t bl[(3 * FO / 16) * (FI / 32) * 64];
    gemm_body<FI, FO, unsigned short>(x, Bfrag, Tbf, Sbf, Ubf, N, bl, blockIdx.x);
}

// ---- propA8: Obf[i] = bf16( T[i] + 2 * sum_p w(p)*Ubf[col[p]] ), w from deg_o on the fly ----
template <int FO>
__global__ void propA8_kernel(const unsigned short* __restrict__ Ubf,
                              const unsigned short* __restrict__ Tbf,
                              const int* __restrict__ fill, const int* __restrict__ deg_o,
                              const int* __restrict__ col,
                              unsigned short* __restrict__ Obf, int N) {
    constexpr int PER = FO / 8;
    unsigned idx = blockIdx.x * blockDim.x + threadIdx.x;
    if (idx >= (unsigned)N * PER) return;
    int i = idx / PER;
    int c = (idx & (PER - 1)) * 8;
    int beg = i * CAP;
    int end = beg + min(fill[i], CAP);
    int dio = deg_o[i];
    float di = (dio > 0) ? -rsqrtf((float)dio) : 0.0f;   // minus folded in
    float acc[8] = {0.f, 0.f, 0.f, 0.f, 0.f, 0.f, 0.f, 0.f};
    for (int p = beg; p < end; ++p) {
        int s = col[p];
        float wv = di * rsqrtf((float)deg_o[s]);   // deg_o[s] >= 1 (edge exists)
        ushort8_t u = *(const ushort8_t*)(Ubf + (size_t)s * FO + c);
#pragma unroll
        for (int j = 0; j < 8; j++) acc[j] = fmaf(wv, bf2f(u[j]), acc[j]);
    }
    ushort8_t tv = *(const ushort8_t*)(Tbf + (size_t)i * FO + c);
    ushort8_t o;
#pragma unroll
    for (int j = 0; j < 8; j++) o[j] = f2bf(bf2f(tv[j]) + 2.f * acc[j]);
    *(ushort8_t*)(Obf + (size_t)i * FO + c) = o;
}

// ---- propC8: h[i] = leaky_relu(BN(S[i] + sum_p w(p)*Bbf[col[p]] + b)), bf16 S/h (h==S ok) ----
template <int FO>
__global__ void propC8_kernel(const unsigned short* __restrict__ Bbf,
                              const unsigned short* __restrict__ Sbf,
                              const int* __restrict__ fill, const int* __restrict__ deg_o,
                              const int* __restrict__ col,
                              const float* __restrict__ b, const float* __restrict__ g,
                              const float* __restrict__ be, const float* __restrict__ m,
                              const float* __restrict__ vv,
                              unsigned short* __restrict__ h, int N) {
    constexpr int PER = FO / 8;
    unsigned idx = blockIdx.x * blockDim.x + threadIdx.x;
    if (idx >= (unsigned)N * PER) return;
    int i = idx / PER;
    int c = (idx & (PER - 1)) * 8;
    int beg = i * CAP;
    int end = beg + min(fill[i], CAP);
    int dio = deg_o[i];
    float di = (dio > 0) ? -rsqrtf((float)dio) : 0.0f;
    float acc[8] = {0.f, 0.f, 0.f, 0.f, 0.f, 0.f, 0.f, 0.f};
    for (int p = beg; p < end; ++p) {
        int s = col[p];
        float wv = di * rsqrtf((float)deg_o[s]);
        ushort8_t u = *(const ushort8_t*)(Bbf + (size_t)s * FO + c);
#pragma unroll
        for (int j = 0; j < 8; j++) acc[j] = fmaf(wv, bf2f(u[j]), acc[j]);
    }
    ushort8_t sv = *(const ushort8_t*)(Sbf + (size_t)i * FO + c);
    ushort8_t o;
#pragma unroll
    for (int j = 0; j < 8; j++) {
        int f = c + j;
        float A = g[f] * rsqrtf(vv[f] + BN_EPS);
        float B = be[f] - (m[f] - b[f]) * A;
        float y = (bf2f(sv[j]) + acc[j]) * A + B;
        y = y > 0.0f ? y : 0.01f * y;
        o[j] = f2bf(y);
    }
    *(ushort8_t*)(h + (size_t)i * FO + c) = o;
}

// ---- mean pool: thread = (node-lane, feature-quad); bf16 h, 8B loads ----
__global__ __launch_bounds__(256) void pool3_kernel(
        const unsigned short* __restrict__ h, const int* __restrict__ batch,
        float* __restrict__ pool, float* __restrict__ cnt, int N) {
    __shared__ float sp[NG * 16];
    __shared__ float sc[NG];
    int t = threadIdx.x;
    for (int i = t; i < NG * 16; i += 256) sp[i] = 0.f;
    for (int i = t; i < NG; i += 256) sc[i] = 0.f;
    __syncthreads();
    const int f4 = (t & 3) * 4;      // feature quad
    const int nl = t >> 2;           // node lane 0..63
    const int base = blockIdx.x * PNPB;
    const int nEnd = min(base + PNPB, N);
    float4 acc = make_float4(0.f, 0.f, 0.f, 0.f);
    float cacc = 0.f;
    int gcur = -1;
    for (int n = base + nl; n < nEnd; n += 64) {
        int g = batch[n];
        if (g != gcur) {
            if (gcur >= 0) {
                atomicAdd(&sp[gcur * 16 + f4 + 0], acc.x);
                atomicAdd(&sp[gcur * 16 + f4 + 1], acc.y);
                atomicAdd(&sp[gcur * 16 + f4 + 2], acc.z);
                atomicAdd(&sp[gcur * 16 + f4 + 3], acc.w);
                if (f4 == 0) atomicAdd(&sc[gcur], cacc);
            }
            gcur = g; acc = make_float4(0.f, 0.f, 0.f, 0.f); cacc = 0.f;
        }
        ushort4_t hv = *(const ushort4_t*)(h + (size_t)n * 16 + f4);
        acc.x += bf2f(hv.x); acc.y += bf2f(hv.y);
        acc.z += bf2f(hv.z); acc.w += bf2f(hv.w);
        cacc += 1.f;
    }
    if (gcur >= 0) {
        atomicAdd(&sp[gcur * 16 + f4 + 0], acc.x);
        atomicAdd(&sp[gcur * 16 + f4 + 1], acc.y);
        atomicAdd(&sp[gcur * 16 + f4 + 2], acc.z);
        atomicAdd(&sp[gcur * 16 + f4 + 3], acc.w);
        if (f4 == 0) atomicAdd(&sc[gcur], cacc);
    }
    __syncthreads();
    for (int i = t; i < NG * 16; i += 256)
        if (sp[i] != 0.f) unsafeAtomicAdd(&pool[i], sp[i]);
    for (int i = t; i < NG; i += 256)
        if (sc[i] != 0.f) unsafeAtomicAdd(&cnt[i], sc[i]);
}

// ---------------- final linear head ----------------
__global__ void final_kernel(const float* __restrict__ pool, const float* __restrict__ cnt,
                             const float* __restrict__ lw, const float* __restrict__ lb,
                             float* __restrict__ out) {
    int idx = threadIdx.x;
    if (idx >= NG * 2) return;
    int g = idx >> 1;
    int c = idx & 1;
    float inv = 1.0f / fmaxf(cnt[g], 1.0f);
    float acc = 0.0f;
#pragma unroll
    for (int f = 0; f < 16; f++) acc += pool[g * 16 + f] * lw[c * 16 + f];
    out[idx] = acc * inv + lb[c];
}

extern "C" void kernel_launch(void* const* d_in, const int* in_sizes, int n_in,
                              void* d_out, int out_size, void* d_ws, size_t ws_size,
                              hipStream_t stream) {
    const float* x    = (const float*)d_in[0];
    const int*   ei   = (const int*)d_in[1];
    const int*   batch= (const int*)d_in[2];
    const float* W1 = (const float*)d_in[3];
    const float* b1 = (const float*)d_in[4];
    const float* g1 = (const float*)d_in[5];
    const float* be1= (const float*)d_in[6];
    const float* m1 = (const float*)d_in[7];
    const float* v1 = (const float*)d_in[8];
    const float* W2 = (const float*)d_in[9];
    const float* b2 = (const float*)d_in[10];
    const float* g2 = (const float*)d_in[11];
    const float* be2= (const float*)d_in[12];
    const float* m2 = (const float*)d_in[13];
    const float* v2 = (const float*)d_in[14];
    const float* W3 = (const float*)d_in[15];
    const float* b3 = (const float*)d_in[16];
    const float* g3 = (const float*)d_in[17];
    const float* be3= (const float*)d_in[18];
    const float* m3 = (const float*)d_in[19];
    const float* v3 = (const float*)d_in[20];
    const float* lw = (const float*)d_in[21];
    const float* lb = (const float*)d_in[22];

    const int* src = ei;            // edge_index[0]
    const int* dst = ei + NE;       // edge_index[1]

    float* ws = (float*)d_ws;
    // ---- workspace layout (4-byte units, 16B-aligned; ~75 MB total) ----
    size_t off = 0;
    int*   fill  = (int*)(ws + off); off += NN;    // in-degree / slot counters
    int*   deg_o = (int*)(ws + off); off += NN;    // out-degree (weights on the fly)
    float* pool  = ws + off; off += NG * 16;
    float* cnt   = ws + off; off += NG;
    size_t zero_bytes = off * sizeof(float);       // one memset covers all of the above
    int*   col   = (int*)(ws + off); off += (size_t)NN * CAP;  // fixed-stride CSR cols
    unsigned short* Tbf  = (unsigned short*)(ws + off); off += (size_t)NN * 32;  // NN*64 bf16
    unsigned short* Ubf  = (unsigned short*)(ws + off); off += (size_t)NN * 32;
    unsigned short* Bbbf = (unsigned short*)(ws + off); off += (size_t)NN * 32;
    unsigned short* S1bf = (unsigned short*)(ws + off); off += (size_t)NN * 32;  // S1 / h1
    unsigned short* S2bf = (unsigned short*)(ws + off); off += (size_t)NN * 16;  // S2 / h2
    unsigned short* S3bf = (unsigned short*)(ws + off); off += (size_t)NN * 8;   // S3 / h3
    unsigned short* Bf1  = (unsigned short*)(ws + off); off += 12288;  // 24576 bf16
    unsigned short* Bf2  = (unsigned short*)(ws + off); off += 3072;   //  6144 bf16
    unsigned short* Bf3  = (unsigned short*)(ws + off); off += 768;    //  1536 bf16

    hipMemsetAsync(ws, 0, zero_bytes, stream);

    // ---- prepB first (stream-ordered: Bf1 complete before fused1's gemm blocks) ----
    prepB_all_kernel<<<16, BS, 0, stream>>>(W1, W2, W3, Bf1, Bf2, Bf3);

    // ---- fused: CSR scatter + gemm layer-1 in one heterogeneous launch ----
    fused1_kernel<<<NB_SCAT + NB_G1, 256, 0, stream>>>(
        src, dst, fill, deg_o, col, Bf1, x, Tbf, S1bf, Ubf, NE, NN);

    // ---- layer 1 props ----
    propA8_kernel<64><<<cdiv((long long)NN * 8, BS), BS, 0, stream>>>(Ubf, Tbf, fill, deg_o,
                                                                      col, Bbbf, NN);
    propC8_kernel<64><<<cdiv((long long)NN * 8, BS), BS, 0, stream>>>(Bbbf, S1bf, fill, deg_o,
                                                                      col, b1, g1, be1, m1, v1,
                                                                      S1bf, NN);
    // ---- layer 2: 64 -> 32 ----
    gemmM_kernel<64, 32><<<cdiv(NN, 64), 256, 0, stream>>>(S1bf, Bf2, Tbf, S2bf, Ubf, NN);
    propA8_kernel<32><<<cdiv((long long)NN * 4, BS), BS, 0, stream>>>(Ubf, Tbf, fill, deg_o,
                                                                      col, Bbbf, NN);
    propC8_kernel<32><<<cdiv((long long)NN * 4, BS), BS, 0, stream>>>(Bbbf, S2bf, fill, deg_o,
                                                                      col, b2, g2, be2, m2, v2,
                                                                      S2bf, NN);
    // ---- layer 3: 32 -> 16 ----
    gemmM_kernel<32, 16><<<cdiv(NN, 64), 256, 0, stream>>>(S2bf, Bf3, Tbf, S3bf, Ubf, NN);
    propA8_kernel<16><<<cdiv((long long)NN * 2, BS), BS, 0, stream>>>(Ubf, Tbf, fill, deg_o,
                                                                      col, Bbbf, NN);
    propC8_kernel<16><<<cdiv((long long)NN * 2, BS), BS, 0, stream>>>(Bbbf, S3bf, fill, deg_o,
                                                                      col, b3, g3, be3, m3, v3,
                                                                      S3bf, NN);
    // ---- pool + head ----
    pool3_kernel<<<cdiv(NN, PNPB), 256, 0, stream>>>(S3bf, batch, pool, cnt, NN);
    final_kernel<<<1, 128, 0, stream>>>(pool, cnt, lw, lb, (float*)d_out);
}

// Round 15
// 333.306 us; speedup vs baseline: 1.4680x; 1.0821x over previous
//
#include <hip/hip_runtime.h>
#include <hip/hip_bf16.h>

// Problem constants (match reference)
#define NN 100000   // nodes
#define NE 640000   // edges
#define NG 64       // graphs
#define BN_EPS 1e-5f

#define BS 256      // block size
#define PNPB 256    // nodes per block in pool
#define CAP 32      // fixed CSR slots per row (P(indeg>=32) ~ 1e-9; wrap-guarded)

// fused1: interleaved heterogeneous grid. 4:5 scatter:gemm per 9-block group
// (matches 1250:1563). Interleave keeps both types co-resident for the whole
// dispatch (R14: sequential ranges -> overlap only at the boundary, 91us).
#define NB_SCAT 1250                 // cdiv(NE, 512)
#define NB_G1   1563                 // cdiv(NN, 64)
#define NB_F1   (313 * 9)            // 2817 (guards trim the excess)

typedef __attribute__((ext_vector_type(8))) unsigned short ushort8_t;
typedef __attribute__((ext_vector_type(4))) unsigned short ushort4_t;
typedef __attribute__((ext_vector_type(8))) short bf16x8_t;    // MFMA A/B frag (4 VGPR)
typedef __attribute__((ext_vector_type(4))) float floatx4_t;   // MFMA C/D frag

static inline int cdiv(long long a, int b) { return (int)((a + b - 1) / b); }

__device__ __forceinline__ float bf2f(unsigned short u) {
    union { unsigned int i; float f; } c; c.i = ((unsigned int)u) << 16; return c.f;
}
__device__ __forceinline__ unsigned short f2bf(float f) {   // RNE
    unsigned int u = __float_as_uint(f);
    u += 0x7fffu + ((u >> 16) & 1u);
    return (unsigned short)(u >> 16);
}

// ---- prepB piece: Bcat = [W2 | W1 | W0-W2] (FI x 3FO) in MFMA B-fragment layout ----
template <int FI, int FO>
__device__ __forceinline__ void prep_one(const float* __restrict__ W,
                                         unsigned short* __restrict__ Bfrag, int id) {
    constexpr int NS = FI / 32;
    int lane = id & 63;
    int s = (id >> 6) % NS;
    int t = (id >> 6) / NS;
    int n = t * 16 + (lane & 15);
    int kbase = s * 32 + (lane >> 4) * 8;
    int sec = n / FO;        // 0 -> W2, 1 -> W1, 2 -> W0 - W2
    int nc  = n % FO;
    ushort8_t out;
#pragma unroll
    for (int j = 0; j < 8; j++) {
        int k = kbase + j;
        float v;
        if (sec == 0)      v = W[(size_t)(2 * FI + k) * FO + nc];
        else if (sec == 1) v = W[(size_t)(1 * FI + k) * FO + nc];
        else               v = W[(size_t)(0 * FI + k) * FO + nc]
                             - W[(size_t)(2 * FI + k) * FO + nc];
        out[j] = f2bf(v);
    }
    *(ushort8_t*)(Bfrag + (size_t)id * 8) = out;
}

// Separate launch, stream-ordered BEFORE any consumer of Bf1/2/3 (R13 race lesson).
__global__ void prepB_all_kernel(const float* __restrict__ W1, const float* __restrict__ W2,
                                 const float* __restrict__ W3,
                                 unsigned short* __restrict__ Bf1,
                                 unsigned short* __restrict__ Bf2,
                                 unsigned short* __restrict__ Bf3) {
    int id = blockIdx.x * blockDim.x + threadIdx.x;
    if (id < 3072)      prep_one<128, 64>(W1, Bf1, id);            // 12*4*64
    else if (id < 3840) prep_one<64, 32>(W2, Bf2, id - 3072);      //  6*2*64
    else if (id < 4032) prep_one<32, 16>(W3, Bf3, id - 3840);      //  3*1*64
}

// ---- gemm body (LDS-staged B), for standalone layers 2/3 ----
template <int FI, int FO, typename TI>
__device__ __forceinline__ void gemm_body(
        const TI* __restrict__ x, const unsigned short* __restrict__ Bfrag,
        unsigned short* __restrict__ Tbf, unsigned short* __restrict__ Sbf,
        unsigned short* __restrict__ Ubf, int N, ushort8_t* bl, int gblk) {
    constexpr int NT = 3 * FO / 16;   // n-tiles
    constexpr int NS = FI / 32;       // k-steps
    constexpr int NFRAG = NT * NS;

    const ushort8_t* bsrc = (const ushort8_t*)Bfrag;
    for (int q = threadIdx.x; q < NFRAG * 64; q += 256) bl[q] = bsrc[q];
    __syncthreads();

    const int lane = threadIdx.x & 63;
    const int wave = threadIdx.x >> 6;
    const int m0   = gblk * 64 + wave * 16;
    const int quad = lane >> 4;
    const int mrow = m0 + (lane & 15);

    floatx4_t acc[NT];
#pragma unroll
    for (int t = 0; t < NT; t++) acc[t] = (floatx4_t){0.f, 0.f, 0.f, 0.f};

#pragma unroll
    for (int s = 0; s < NS; s++) {
        bf16x8_t a;
        if (mrow < N) {
            const unsigned short* ap = (const unsigned short*)x
                                     + (size_t)mrow * FI + s * 32 + quad * 8;
            a = *(const bf16x8_t*)ap;   // bf16 bits
        } else {
            a = (bf16x8_t){0, 0, 0, 0, 0, 0, 0, 0};
        }
#pragma unroll
        for (int t = 0; t < NT; t++) {
            bf16x8_t b = *(const bf16x8_t*)&bl[(t * NS + s) * 64 + lane];
            acc[t] = __builtin_amdgcn_mfma_f32_16x16x32_bf16(a, b, acc[t], 0, 0, 0);
        }
    }
    // C/D layout: col = lane&15, row = quad*4 + reg   [verified m89/m91]
#pragma unroll
    for (int t = 0; t < NT; t++) {
        int n   = t * 16 + (lane & 15);
        int sec = (t * 16) / FO;
        int nc  = n % FO;
#pragma unroll
        for (int r = 0; r < 4; r++) {
            int m = m0 + quad * 4 + r;
            if (m >= N) continue;
            unsigned short v = f2bf(acc[t][r]);
            size_t o = (size_t)m * FO + nc;
            if (sec == 0)      Ubf[o] = v;
            else if (sec == 1) Tbf[o] = v;
            else               Sbf[o] = v;
        }
    }
}

// ---- fused1: interleaved [scatter | gemm layer-1], NO LDS ----
// Gemm path reads Bfrag straight from global (48KB, L2-hot): standalone that is
// latency-bound (R8), but here the latency hides inside scatter's atomic shadow,
// and LDS=0 restores scatter occupancy (R14: 48KB static LDS capped ALL blocks
// at 3/CU, occupancy 41%->28%).
__global__ __launch_bounds__(256) void fused1_kernel(
        const int* __restrict__ src, const int* __restrict__ dst,
        int* __restrict__ fill, int* __restrict__ deg_o, int* __restrict__ col,
        const unsigned short* __restrict__ Bf1,
        const float* __restrict__ x, unsigned short* __restrict__ Tbf,
        unsigned short* __restrict__ Sbf, unsigned short* __restrict__ Ubf,
        int E, int N) {
    const int g = blockIdx.x / 9;
    const int r = blockIdx.x % 9;
    if (r < 4) {
        // ---------------- scatter path ----------------
        int sid = g * 4 + r;
        if (sid >= NB_SCAT) return;
        int e0 = (sid * 256 + threadIdx.x) * 2;
#pragma unroll
        for (int q = 0; q < 2; q++) {
            int e = e0 + q;
            if (e < E) {
                int s = src[e], d = dst[e];
                if (s != d) {
                    atomicAdd(&deg_o[s], 1);
                    int pos = atomicAdd(&fill[d], 1) & (CAP - 1);   // wrap guard
                    col[(size_t)d * CAP + pos] = s;
                }
            }
        }
        return;
    }
    // ---------------- gemm layer-1 path (direct-global B) ----------------
    int gblk = g * 5 + (r - 4);
    if (gblk >= NB_G1) return;
    constexpr int NT = 12;   // 3*64/16
    constexpr int NS = 4;    // 128/32
    const int lane = threadIdx.x & 63;
    const int wave = threadIdx.x >> 6;
    const int m0   = gblk * 64 + wave * 16;
    const int quad = lane >> 4;
    const int mrow = m0 + (lane & 15);

    floatx4_t acc[NT];
#pragma unroll
    for (int t = 0; t < NT; t++) acc[t] = (floatx4_t){0.f, 0.f, 0.f, 0.f};

#pragma unroll
    for (int s = 0; s < NS; s++) {
        bf16x8_t a;
        if (mrow < N) {
            const float* ap = x + (size_t)mrow * 128 + s * 32 + quad * 8;
            float4 a0 = *(const float4*)(ap);
            float4 a1 = *(const float4*)(ap + 4);
            a[0] = (short)f2bf(a0.x); a[1] = (short)f2bf(a0.y);
            a[2] = (short)f2bf(a0.z); a[3] = (short)f2bf(a0.w);
            a[4] = (short)f2bf(a1.x); a[5] = (short)f2bf(a1.y);
            a[6] = (short)f2bf(a1.z); a[7] = (short)f2bf(a1.w);
        } else {
            a = (bf16x8_t){0, 0, 0, 0, 0, 0, 0, 0};
        }
#pragma unroll
        for (int t = 0; t < NT; t++) {
            bf16x8_t b = *(const bf16x8_t*)(Bf1 + ((size_t)(t * NS + s) * 64 + lane) * 8);
            acc[t] = __builtin_amdgcn_mfma_f32_16x16x32_bf16(a, b, acc[t], 0, 0, 0);
        }
    }
#pragma unroll
    for (int t = 0; t < NT; t++) {
        int n   = t * 16 + (lane & 15);
        int sec = (t * 16) / 64;
        int nc  = n % 64;
#pragma unroll
        for (int r2 = 0; r2 < 4; r2++) {
            int m = m0 + quad * 4 + r2;
            if (m >= N) continue;
            unsigned short v = f2bf(acc[t][r2]);
            size_t o = (size_t)m * 64 + nc;
            if (sec == 0)      Ubf[o] = v;
            else if (sec == 1) Tbf[o] = v;
            else               Sbf[o] = v;
        }
    }
}

// ---- rdeg: rsqrt table so props do 1 mul/edge instead of load+cvt+rsqrt x6 kernels ----
__global__ void rdeg_kernel(const int* __restrict__ deg_o, float* __restrict__ rdeg, int N) {
    int i = blockIdx.x * blockDim.x + threadIdx.x;
    if (i < N) {
        int d = deg_o[i];
        rdeg[i] = (d > 0) ? rsqrtf((float)d) : 0.0f;
    }
}

// ---- standalone gemm for layers 2/3 (bf16 input, LDS-staged B) ----
template <int FI, int FO>
__global__ __launch_bounds__(256) void gemmM_kernel(
        const unsigned short* __restrict__ x, const unsigned short* __restrict__ Bfrag,
        unsigned short* __restrict__ Tbf, unsigned short* __restrict__ Sbf,
        unsigned short* __restrict__ Ubf, int N) {
    __shared__ ushort8_t bl[(3 * FO / 16) * (FI / 32) * 64];
    gemm_body<FI, FO, unsigned short>(x, Bfrag, Tbf, Sbf, Ubf, N, bl, blockIdx.x);
}

// ---- propA8: Obf[i] = bf16( T[i] + 2 * sum_p w(p)*Ubf[col[p]] ) ----
// 2-way unrolled edge loop: pairs of independent col->gather chains halve the
// dependent-latency depth. w = -rdeg[i]*rdeg[s] from the precomputed table.
template <int FO>
__global__ void propA8_kernel(const unsigned short* __restrict__ Ubf,
                              const unsigned short* __restrict__ Tbf,
                              const int* __restrict__ fill, const float* __restrict__ rdeg,
                              const int* __restrict__ col,
                              unsigned short* __restrict__ Obf, int N) {
    constexpr int PER = FO / 8;
    unsigned idx = blockIdx.x * blockDim.x + threadIdx.x;
    if (idx >= (unsigned)N * PER) return;
    int i = idx / PER;
    int c = (idx & (PER - 1)) * 8;
    int beg = i * CAP;
    int end = beg + min(fill[i], CAP);
    float di = -rdeg[i];
    float acc[8] = {0.f, 0.f, 0.f, 0.f, 0.f, 0.f, 0.f, 0.f};
    int p = beg;
    for (; p + 2 <= end; p += 2) {
        int s0 = col[p], s1 = col[p + 1];
        float w0 = di * rdeg[s0], w1 = di * rdeg[s1];
        ushort8_t u0 = *(const ushort8_t*)(Ubf + (size_t)s0 * FO + c);
        ushort8_t u1 = *(const ushort8_t*)(Ubf + (size_t)s1 * FO + c);
#pragma unroll
        for (int j = 0; j < 8; j++) {
            acc[j] = fmaf(w0, bf2f(u0[j]), acc[j]);
            acc[j] = fmaf(w1, bf2f(u1[j]), acc[j]);
        }
    }
    if (p < end) {
        int s0 = col[p];
        float w0 = di * rdeg[s0];
        ushort8_t u0 = *(const ushort8_t*)(Ubf + (size_t)s0 * FO + c);
#pragma unroll
        for (int j = 0; j < 8; j++) acc[j] = fmaf(w0, bf2f(u0[j]), acc[j]);
    }
    ushort8_t tv = *(const ushort8_t*)(Tbf + (size_t)i * FO + c);
    ushort8_t o;
#pragma unroll
    for (int j = 0; j < 8; j++) o[j] = f2bf(bf2f(tv[j]) + 2.f * acc[j]);
    *(ushort8_t*)(Obf + (size_t)i * FO + c) = o;
}

// ---- propC8: h[i] = leaky_relu(BN(S[i] + sum_p w(p)*Bbf[col[p]] + b)), bf16 S/h (h==S ok) ----
template <int FO>
__global__ void propC8_kernel(const unsigned short* __restrict__ Bbf,
                              const unsigned short* __restrict__ Sbf,
                              const int* __restrict__ fill, const float* __restrict__ rdeg,
                              const int* __restrict__ col,
                              const float* __restrict__ b, const float* __restrict__ g,
                              const float* __restrict__ be, const float* __restrict__ m,
                              const float* __restrict__ vv,
                              unsigned short* __restrict__ h, int N) {
    constexpr int PER = FO / 8;
    unsigned idx = blockIdx.x * blockDim.x + threadIdx.x;
    if (idx >= (unsigned)N * PER) return;
    int i = idx / PER;
    int c = (idx & (PER - 1)) * 8;
    int beg = i * CAP;
    int end = beg + min(fill[i], CAP);
    float di = -rdeg[i];
    float acc[8] = {0.f, 0.f, 0.f, 0.f, 0.f, 0.f, 0.f, 0.f};
    int p = beg;
    for (; p + 2 <= end; p += 2) {
        int s0 = col[p], s1 = col[p + 1];
        float w0 = di * rdeg[s0], w1 = di * rdeg[s1];
        ushort8_t u0 = *(const ushort8_t*)(Bbf + (size_t)s0 * FO + c);
        ushort8_t u1 = *(const ushort8_t*)(Bbf + (size_t)s1 * FO + c);
#pragma unroll
        for (int j = 0; j < 8; j++) {
            acc[j] = fmaf(w0, bf2f(u0[j]), acc[j]);
            acc[j] = fmaf(w1, bf2f(u1[j]), acc[j]);
        }
    }
    if (p < end) {
        int s0 = col[p];
        float w0 = di * rdeg[s0];
        ushort8_t u0 = *(const ushort8_t*)(Bbf + (size_t)s0 * FO + c);
#pragma unroll
        for (int j = 0; j < 8; j++) acc[j] = fmaf(w0, bf2f(u0[j]), acc[j]);
    }
    ushort8_t sv = *(const ushort8_t*)(Sbf + (size_t)i * FO + c);
    ushort8_t o;
#pragma unroll
    for (int j = 0; j < 8; j++) {
        int f = c + j;
        float A = g[f] * rsqrtf(vv[f] + BN_EPS);
        float B = be[f] - (m[f] - b[f]) * A;
        float y = (bf2f(sv[j]) + acc[j]) * A + B;
        y = y > 0.0f ? y : 0.01f * y;
        o[j] = f2bf(y);
    }
    *(ushort8_t*)(h + (size_t)i * FO + c) = o;
}

// ---- mean pool: thread = (node-lane, feature-quad); bf16 h, 8B loads ----
__global__ __launch_bounds__(256) void pool3_kernel(
        const unsigned short* __restrict__ h, const int* __restrict__ batch,
        float* __restrict__ pool, float* __restrict__ cnt, int N) {
    __shared__ float sp[NG * 16];
    __shared__ float sc[NG];
    int t = threadIdx.x;
    for (int i = t; i < NG * 16; i += 256) sp[i] = 0.f;
    for (int i = t; i < NG; i += 256) sc[i] = 0.f;
    __syncthreads();
    const int f4 = (t & 3) * 4;      // feature quad
    const int nl = t >> 2;           // node lane 0..63
    const int base = blockIdx.x * PNPB;
    const int nEnd = min(base + PNPB, N);
    float4 acc = make_float4(0.f, 0.f, 0.f, 0.f);
    float cacc = 0.f;
    int gcur = -1;
    for (int n = base + nl; n < nEnd; n += 64) {
        int g = batch[n];
        if (g != gcur) {
            if (gcur >= 0) {
                atomicAdd(&sp[gcur * 16 + f4 + 0], acc.x);
                atomicAdd(&sp[gcur * 16 + f4 + 1], acc.y);
                atomicAdd(&sp[gcur * 16 + f4 + 2], acc.z);
                atomicAdd(&sp[gcur * 16 + f4 + 3], acc.w);
                if (f4 == 0) atomicAdd(&sc[gcur], cacc);
            }
            gcur = g; acc = make_float4(0.f, 0.f, 0.f, 0.f); cacc = 0.f;
        }
        ushort4_t hv = *(const ushort4_t*)(h + (size_t)n * 16 + f4);
        acc.x += bf2f(hv.x); acc.y += bf2f(hv.y);
        acc.z += bf2f(hv.z); acc.w += bf2f(hv.w);
        cacc += 1.f;
    }
    if (gcur >= 0) {
        atomicAdd(&sp[gcur * 16 + f4 + 0], acc.x);
        atomicAdd(&sp[gcur * 16 + f4 + 1], acc.y);
        atomicAdd(&sp[gcur * 16 + f4 + 2], acc.z);
        atomicAdd(&sp[gcur * 16 + f4 + 3], acc.w);
        if (f4 == 0) atomicAdd(&sc[gcur], cacc);
    }
    __syncthreads();
    for (int i = t; i < NG * 16; i += 256)
        if (sp[i] != 0.f) unsafeAtomicAdd(&pool[i], sp[i]);
    for (int i = t; i < NG; i += 256)
        if (sc[i] != 0.f) unsafeAtomicAdd(&cnt[i], sc[i]);
}

// ---------------- final linear head ----------------
__global__ void final_kernel(const float* __restrict__ pool, const float* __restrict__ cnt,
                             const float* __restrict__ lw, const float* __restrict__ lb,
                             float* __restrict__ out) {
    int idx = threadIdx.x;
    if (idx >= NG * 2) return;
    int g = idx >> 1;
    int c = idx & 1;
    float inv = 1.0f / fmaxf(cnt[g], 1.0f);
    float acc = 0.0f;
#pragma unroll
    for (int f = 0; f < 16; f++) acc += pool[g * 16 + f] * lw[c * 16 + f];
    out[idx] = acc * inv + lb[c];
}

extern "C" void kernel_launch(void* const* d_in, const int* in_sizes, int n_in,
                              void* d_out, int out_size, void* d_ws, size_t ws_size,
                              hipStream_t stream) {
    const float* x    = (const float*)d_in[0];
    const int*   ei   = (const int*)d_in[1];
    const int*   batch= (const int*)d_in[2];
    const float* W1 = (const float*)d_in[3];
    const float* b1 = (const float*)d_in[4];
    const float* g1 = (const float*)d_in[5];
    const float* be1= (const float*)d_in[6];
    const float* m1 = (const float*)d_in[7];
    const float* v1 = (const float*)d_in[8];
    const float* W2 = (const float*)d_in[9];
    const float* b2 = (const float*)d_in[10];
    const float* g2 = (const float*)d_in[11];
    const float* be2= (const float*)d_in[12];
    const float* m2 = (const float*)d_in[13];
    const float* v2 = (const float*)d_in[14];
    const float* W3 = (const float*)d_in[15];
    const float* b3 = (const float*)d_in[16];
    const float* g3 = (const float*)d_in[17];
    const float* be3= (const float*)d_in[18];
    const float* m3 = (const float*)d_in[19];
    const float* v3 = (const float*)d_in[20];
    const float* lw = (const float*)d_in[21];
    const float* lb = (const float*)d_in[22];

    const int* src = ei;            // edge_index[0]
    const int* dst = ei + NE;       // edge_index[1]

    float* ws = (float*)d_ws;
    // ---- workspace layout (4-byte units, 16B-aligned; ~75 MB total) ----
    size_t off = 0;
    int*   fill  = (int*)(ws + off); off += NN;    // in-degree / slot counters
    int*   deg_o = (int*)(ws + off); off += NN;    // out-degree
    float* pool  = ws + off; off += NG * 16;
    float* cnt   = ws + off; off += NG;
    size_t zero_bytes = off * sizeof(float);       // one memset covers all of the above
    float* rdeg  = ws + off; off += NN;            // rsqrt(deg_o) table
    int*   col   = (int*)(ws + off); off += (size_t)NN * CAP;  // fixed-stride CSR cols
    unsigned short* Tbf  = (unsigned short*)(ws + off); off += (size_t)NN * 32;  // NN*64 bf16
    unsigned short* Ubf  = (unsigned short*)(ws + off); off += (size_t)NN * 32;
    unsigned short* Bbbf = (unsigned short*)(ws + off); off += (size_t)NN * 32;
    unsigned short* S1bf = (unsigned short*)(ws + off); off += (size_t)NN * 32;  // S1 / h1
    unsigned short* S2bf = (unsigned short*)(ws + off); off += (size_t)NN * 16;  // S2 / h2
    unsigned short* S3bf = (unsigned short*)(ws + off); off += (size_t)NN * 8;   // S3 / h3
    unsigned short* Bf1  = (unsigned short*)(ws + off); off += 12288;  // 24576 bf16
    unsigned short* Bf2  = (unsigned short*)(ws + off); off += 3072;   //  6144 bf16
    unsigned short* Bf3  = (unsigned short*)(ws + off); off += 768;    //  1536 bf16

    hipMemsetAsync(ws, 0, zero_bytes, stream);

    // ---- prepB first (stream-ordered: Bf1 complete before fused1's gemm blocks) ----
    prepB_all_kernel<<<16, BS, 0, stream>>>(W1, W2, W3, Bf1, Bf2, Bf3);

    // ---- fused: interleaved CSR scatter + gemm layer-1 ----
    fused1_kernel<<<NB_F1, 256, 0, stream>>>(
        src, dst, fill, deg_o, col, Bf1, x, Tbf, S1bf, Ubf, NE, NN);

    // ---- rsqrt(deg) table ----
    rdeg_kernel<<<cdiv(NN, BS), BS, 0, stream>>>(deg_o, rdeg, NN);

    // ---- layer 1 props ----
    propA8_kernel<64><<<cdiv((long long)NN * 8, BS), BS, 0, stream>>>(Ubf, Tbf, fill, rdeg,
                                                                      col, Bbbf, NN);
    propC8_kernel<64><<<cdiv((long long)NN * 8, BS), BS, 0, stream>>>(Bbbf, S1bf, fill, rdeg,
                                                                      col, b1, g1, be1, m1, v1,
                                                                      S1bf, NN);
    // ---- layer 2: 64 -> 32 ----
    gemmM_kernel<64, 32><<<cdiv(NN, 64), 256, 0, stream>>>(S1bf, Bf2, Tbf, S2bf, Ubf, NN);
    propA8_kernel<32><<<cdiv((long long)NN * 4, BS), BS, 0, stream>>>(Ubf, Tbf, fill, rdeg,
                                                                      col, Bbbf, NN);
    propC8_kernel<32><<<cdiv((long long)NN * 4, BS), BS, 0, stream>>>(Bbbf, S2bf, fill, rdeg,
                                                                      col, b2, g2, be2, m2, v2,
                                                                      S2bf, NN);
    // ---- layer 3: 32 -> 16 ----
    gemmM_kernel<32, 16><<<cdiv(NN, 64), 256, 0, stream>>>(S2bf, Bf3, Tbf, S3bf, Ubf, NN);
    propA8_kernel<16><<<cdiv((long long)NN * 2, BS), BS, 0, stream>>>(Ubf, Tbf, fill, rdeg,
                                                                      col, Bbbf, NN);
    propC8_kernel<16><<<cdiv((long long)NN * 2, BS), BS, 0, stream>>>(Bbbf, S3bf, fill, rdeg,
                                                                      col, b3, g3, be3, m3, v3,
                                                                      S3bf, NN);
    // ---- pool + head ----
    pool3_kernel<<<cdiv(NN, PNPB), 256, 0, stream>>>(S3bf, batch, pool, cnt, NN);
    final_kernel<<<1, 128, 0, stream>>>(pool, cnt, lw, lb, (float*)d_out);
}